// Round 15
// baseline (183.513 us; speedup 1.0000x reference)
//
#include <hip/hip_runtime.h>
#include <math.h>

typedef unsigned short u16;
typedef unsigned int   u32;
typedef __attribute__((ext_vector_type(8)))  __bf16 bf16x8;
typedef __attribute__((ext_vector_type(16))) float  f32x16;

constexpr int Bc  = 4;
constexpr int Nc  = 2304;
constexpr int KSc = 8;
constexpr int Cc  = 512;
constexpr int Hc  = 8;
constexpr int Dc  = 64;
constexpr int NTc = Nc + KSc;          // 2312
constexpr int M1c = Bc * NTc;          // 9248
constexpr int N1c = 3 * Cc;            // 1536
constexpr int M2c = Bc * Nc;           // 9216
constexpr int QT256 = Nc / 256;        // 9 query tiles of 256 (2 subtiles of 128)
constexpr int KT64  = NTc / 64;        // 36 full tiles (+8 tail)
constexpr float LOG2E = 1.4426950408889634f;

__device__ __forceinline__ u32 f2bf1(float f) {
    u32 u = __float_as_uint(f);
    return (u + 0x7fffu + ((u >> 16) & 1u)) >> 16;   // RNE bf16
}
__device__ __forceinline__ u32 pk2(float lo, float hi) {
    u32 ul = __float_as_uint(lo);
    u32 uh = __float_as_uint(hi);
    ul = (ul + 0x7fffu + ((ul >> 16) & 1u)) >> 16;
    uh = (uh + 0x7fffu + ((uh >> 16) & 1u)) & 0xffff0000u;
    return ul | uh;
}
__device__ __forceinline__ float bf2f(u16 x) {
    return __uint_as_float(((u32)x) << 16);
}
__device__ __forceinline__ u32 pkb(float lo, float hi) {
    union { u32 u; __bf16 h[2]; } t;
    t.h[0] = (__bf16)lo; t.h[1] = (__bf16)hi;
    return t.u;
}
// async global->LDS, 16B per lane; LDS dest = wave base + lane*16 (linear)
__device__ __forceinline__ void gll16(const u16* g, char* l) {
    __builtin_amdgcn_global_load_lds(
        (const __attribute__((address_space(1))) unsigned int*)g,
        (__attribute__((address_space(3))) unsigned int*)l, 16, 0, 0);
}

#define MFMA32(A, B, C) __builtin_amdgcn_mfma_f32_32x32x16_bf16(A, B, C, 0, 0, 0)

union U4 { u32 u[4]; bf16x8 f; };

// ---------------------------------------------------------------------------
// concat(X,S) -> bf16 A [M1][512]
// ---------------------------------------------------------------------------
__global__ __launch_bounds__(256)
void cvt_concat(const float* __restrict__ X, const float* __restrict__ S,
                u16* __restrict__ A)
{
    const int id  = blockIdx.x * 256 + threadIdx.x;
    const int row = id >> 6;
    const int ch  = (id & 63) * 8;
    const int b = row / NTc, t = row - b * NTc;
    const float* src = (t < Nc) ? X + ((size_t)(b * Nc + t)) * Cc + ch
                                : S + ((size_t)(b * KSc + (t - Nc))) * Cc + ch;
    const float4 v0 = ((const float4*)src)[0];
    const float4 v1 = ((const float4*)src)[1];
    u32 w[4];
    w[0] = pk2(v0.x, v0.y); w[1] = pk2(v0.z, v0.w);
    w[2] = pk2(v1.x, v1.y); w[3] = pk2(v1.z, v1.w);
    *(uint4*)(A + (size_t)row * Cc + ch) = *(const uint4*)w;
}

// ---------------------------------------------------------------------------
// Transpose-cast weights: W [512][Nn] f32 -> WT [Nn][512] bf16 (+ lo part)
// ---------------------------------------------------------------------------
template<bool LO>
__global__ __launch_bounds__(256)
void cvt_w(const float* __restrict__ W, int Nn,
           u16* __restrict__ WT, u16* __restrict__ WTl)
{
    __shared__ float Ws[64][68];
    const int n0 = blockIdx.x * 64, k0 = blockIdx.y * 64;
#pragma unroll
    for (int i = 0; i < 4; ++i) {
        const int c = i * 256 + threadIdx.x;
        const int kr = c >> 4, nc = (c & 15) * 4;
        const float4 v = *(const float4*)(W + (size_t)(k0 + kr) * Nn + n0 + nc);
        Ws[kr][nc] = v.x; Ws[kr][nc+1] = v.y; Ws[kr][nc+2] = v.z; Ws[kr][nc+3] = v.w;
    }
    __syncthreads();
#pragma unroll
    for (int i = 0; i < 2; ++i) {
        const int c = i * 256 + threadIdx.x;
        const int n = c >> 3, kc = (c & 7) * 8;
        u32 wh[4], wl[4];
#pragma unroll
        for (int j = 0; j < 4; ++j) {
            const float a = Ws[kc + 2*j][n], bq = Ws[kc + 2*j + 1][n];
            const u32 ha = f2bf1(a), hb = f2bf1(bq);
            wh[j] = ha | (hb << 16);
            if constexpr (LO) {
                const float la = a  - __uint_as_float(ha << 16);
                const float lb = bq - __uint_as_float(hb << 16);
                wl[j] = pk2(la, lb);
            }
        }
        *(uint4*)(WT + (size_t)(n0 + n) * Cc + k0 + kc) = *(const uint4*)wh;
        if constexpr (LO)
            *(uint4*)(WTl + (size_t)(n0 + n) * Cc + k0 + kc) = *(const uint4*)wl;
    }
}

// ---------------------------------------------------------------------------
// V (B,H,Nt,D) bf16 -> Vt (B,H,D,Nt) bf16
// ---------------------------------------------------------------------------
__global__ __launch_bounds__(256)
void transpose_v(const u16* __restrict__ Vbf, u16* __restrict__ Vt)
{
    __shared__ u16 Vs[64][80];
    const int bh = blockIdx.x;
    const int t0 = blockIdx.y * 64;
    const u16* src = Vbf + (size_t)bh * NTc * Dc;
#pragma unroll
    for (int i = 0; i < 2; ++i) {
        const int c = i * 256 + threadIdx.x;
        const int tr = c >> 3, dc = (c & 7) * 8;
        int tg = t0 + tr; if (tg > NTc - 1) tg = NTc - 1;
        const uint4 v = *(const uint4*)(src + (size_t)tg * Dc + dc);
        *(uint4*)&Vs[tr][dc] = v;
    }
    __syncthreads();
#pragma unroll
    for (int i = 0; i < 2; ++i) {
        const int c = i * 256 + threadIdx.x;
        const int d = c >> 3, tch = (c & 7) * 8;
        if (t0 + tch + 7 <= NTc - 1) {
            u16 tmp[8];
#pragma unroll
            for (int j = 0; j < 8; ++j) tmp[j] = Vs[tch + j][d];
            *(uint4*)(Vt + ((size_t)bh * Dc + d) * NTc + t0 + tch) = *(const uint4*)tmp;
        }
    }
}

// ---------------------------------------------------------------------------
// QKV GEMM, bf16 MFMA, global_load_lds double-buffered staging.
// Fused q/k L2-norm epilogue (round-14 verified).
// ---------------------------------------------------------------------------
__global__ __launch_bounds__(256)
void gemm_qkv(const u16* __restrict__ A, const u16* __restrict__ Bw,
              const float* __restrict__ temp,
              u16* __restrict__ Qb, u16* __restrict__ Kb, u16* __restrict__ Vb)
{
    __shared__ __align__(16) u16 lds[2 * 2 * 8192];   // [buf][A/B] 16 KB each
    char* L = (char*)lds;

    const int tid = threadIdx.x;
    const int wid = tid >> 6, lane = tid & 63, hi = lane >> 5, ln = lane & 31;
    const int wm = wid >> 1, wn = wid & 1;
    const int m0 = blockIdx.x * 128, n0 = blockIdx.y * 128;

    const int sr = tid >> 3;
    const int sc = tid & 7;

    f32x16 acc[2][2];
#pragma unroll
    for (int i = 0; i < 2; ++i)
#pragma unroll
        for (int j = 0; j < 2; ++j)
#pragma unroll
            for (int r = 0; r < 16; ++r) acc[i][j][r] = 0.f;

#define QKV_STAGE(BUF, K0)                                                     \
    do {                                                                       \
        char* dA = L + (BUF) * 32768;                                          \
        char* dB = dA + 16384;                                                 \
        _Pragma("unroll")                                                      \
        for (int i_ = 0; i_ < 4; ++i_) {                                       \
            const int row_ = i_ * 32 + sr;                                     \
            const int gc_  = (sc ^ (row_ & 7)) * 8;                            \
            int mg_ = m0 + row_; if (mg_ > M1c - 1) mg_ = M1c - 1;             \
            gll16(A  + (size_t)mg_ * Cc + (K0) + gc_,                          \
                  dA + i_ * 4096 + tid * 16);                                  \
            gll16(Bw + (size_t)(n0 + row_) * Cc + (K0) + gc_,                  \
                  dB + i_ * 4096 + tid * 16);                                  \
        }                                                                      \
    } while (0)

    QKV_STAGE(0, 0);
    __syncthreads();

    for (int k0 = 0; k0 < Cc; k0 += 64) {
        const int cur = (k0 >> 6) & 1;
        if (k0 + 64 < Cc) QKV_STAGE(cur ^ 1, k0 + 64);
        const char* ldsA = L + cur * 32768;
        const char* ldsB = ldsA + 16384;
#pragma unroll
        for (int ks = 0; ks < 4; ++ks) {
            bf16x8 af[2], bfr[2];
#pragma unroll
            for (int f = 0; f < 2; ++f) {
                const int mr = wm * 64 + f * 32 + ln;
                af[f]  = *(const bf16x8*)(ldsA + mr * 128 + (((ks * 2 + hi) ^ (mr & 7)) << 4));
                const int nr = wn * 64 + f * 32 + ln;
                bfr[f] = *(const bf16x8*)(ldsB + nr * 128 + (((ks * 2 + hi) ^ (nr & 7)) << 4));
            }
#pragma unroll
            for (int fm = 0; fm < 2; ++fm)
#pragma unroll
                for (int fn = 0; fn < 2; ++fn)
                    acc[fm][fn] = MFMA32(af[fm], bfr[fn], acc[fm][fn]);
        }
        __syncthreads();
    }
#undef QKV_STAGE

    const int which = n0 >> 9;
    const int hh = ((n0 + wn * 64) >> 6) & 7;

    if (which < 2) {
        const float tsc = (which == 0) ? temp[hh] : 1.0f;
#pragma unroll
        for (int fm = 0; fm < 2; ++fm)
#pragma unroll
            for (int r = 0; r < 16; ++r) {
                float ss = fmaf(acc[fm][0][r], acc[fm][0][r],
                                acc[fm][1][r] * acc[fm][1][r]);
                ss += __shfl_xor(ss, 1);
                ss += __shfl_xor(ss, 2);
                ss += __shfl_xor(ss, 4);
                ss += __shfl_xor(ss, 8);
                ss += __shfl_xor(ss, 16);
                const float scl = tsc / fmaxf(sqrtf(ss), 1e-12f);
                acc[fm][0][r] *= scl;
                acc[fm][1][r] *= scl;
            }
    }

#pragma unroll
    for (int fm = 0; fm < 2; ++fm)
#pragma unroll
        for (int fn = 0; fn < 2; ++fn) {
            const int ng = n0 + wn * 64 + fn * 32 + ln;
            const int h = (ng >> 6) & 7, d = ng & 63;
            u16* base = (which == 0) ? Qb : ((which == 1) ? Kb : Vb);
#pragma unroll
            for (int r = 0; r < 16; ++r) {
                const int mg = m0 + wm * 64 + fm * 32 + (r & 3) + 8 * (r >> 2) + 4 * hi;
                if (mg < M1c) {
                    const int b = mg / NTc, t = mg - b * NTc;
                    base[((size_t)((b * Hc + h) * NTc + t)) * Dc + d] = (u16)f2bf1(acc[fm][fn][r]);
                }
            }
        }
}

// ---------------------------------------------------------------------------
// Out GEMM, split-bf16 3-pass, BK=32 double-buffered global_load_lds staging.
// ---------------------------------------------------------------------------
__global__ __launch_bounds__(256)
void gemm_out(const u16* __restrict__ Ahg, const u16* __restrict__ Alg,
              const u16* __restrict__ Bhg, const u16* __restrict__ Blg,
              float* __restrict__ Out)
{
    __shared__ __align__(16) u16 lds[2 * 12288];      // 2 x 24 KB
    char* L = (char*)lds;

    const int tid = threadIdx.x;
    const int wid = tid >> 6, lane = tid & 63, hi = lane >> 5, ln = lane & 31;
    const int wm = wid >> 1, wn = wid & 1;
    const int m0 = blockIdx.x * 128, n0 = blockIdx.y * 64;
    const int sr2 = tid >> 2;
    const int sc2 = tid & 3;

    f32x16 acc[2];
#pragma unroll
    for (int i = 0; i < 2; ++i)
#pragma unroll
        for (int r = 0; r < 16; ++r) acc[i][r] = 0.f;

#define OUT_STAGE(BUF, K0)                                                     \
    do {                                                                       \
        char* bb = L + (BUF) * 24576;                                          \
        _Pragma("unroll")                                                      \
        for (int i_ = 0; i_ < 2; ++i_) {                                       \
            const int row_ = i_ * 64 + sr2;                                    \
            const int gc_  = (sc2 ^ (row_ & 3)) * 8;                           \
            const size_t go_ = (size_t)(m0 + row_) * Cc + (K0) + gc_;          \
            gll16(Ahg + go_, bb + i_ * 4096 + tid * 16);                       \
            gll16(Alg + go_, bb + 8192 + i_ * 4096 + tid * 16);                \
        }                                                                      \
        {                                                                      \
            const int gc_  = (sc2 ^ (sr2 & 3)) * 8;                            \
            const size_t go_ = (size_t)(n0 + sr2) * Cc + (K0) + gc_;           \
            gll16(Bhg + go_, bb + 16384 + tid * 16);                           \
            gll16(Blg + go_, bb + 20480 + tid * 16);                           \
        }                                                                      \
    } while (0)

    OUT_STAGE(0, 0);
    __syncthreads();

    for (int k0 = 0; k0 < Cc; k0 += 32) {
        const int cur = (k0 >> 5) & 1;
        if (k0 + 32 < Cc) OUT_STAGE(cur ^ 1, k0 + 32);
        const char* bb = L + cur * 24576;
        const char* pAh = bb;
        const char* pAl = bb + 8192;
        const char* pBh = bb + 16384;
        const char* pBl = bb + 20480;
#pragma unroll
        for (int ks = 0; ks < 2; ++ks) {
            bf16x8 afh[2], afl[2], bfh, bfl;
#pragma unroll
            for (int f = 0; f < 2; ++f) {
                const int mr = wm * 64 + f * 32 + ln;
                const int moff = mr * 64 + (((ks * 2 + hi) ^ (mr & 3)) << 4);
                afh[f] = *(const bf16x8*)(pAh + moff);
                afl[f] = *(const bf16x8*)(pAl + moff);
            }
            {
                const int nr = wn * 32 + ln;
                const int noff = nr * 64 + (((ks * 2 + hi) ^ (nr & 3)) << 4);
                bfh = *(const bf16x8*)(pBh + noff);
                bfl = *(const bf16x8*)(pBl + noff);
            }
#pragma unroll
            for (int fm = 0; fm < 2; ++fm) {
                acc[fm] = MFMA32(afh[fm], bfh, acc[fm]);
                acc[fm] = MFMA32(afl[fm], bfh, acc[fm]);
                acc[fm] = MFMA32(afh[fm], bfl, acc[fm]);
            }
        }
        __syncthreads();
    }
#undef OUT_STAGE

#pragma unroll
    for (int fm = 0; fm < 2; ++fm) {
        const int ng = n0 + wn * 32 + ln;
#pragma unroll
        for (int r = 0; r < 16; ++r) {
            const int mg = m0 + wm * 64 + fm * 32 + (r & 3) + 8 * (r >> 2) + 4 * hi;
            Out[(size_t)mg * Cc + ng] = acc[fm][r];
        }
    }
}

// ---------------------------------------------------------------------------
// MFMA flash attention, split-K x2. 4 waves x 256 threads (frozen thread
// layout), now TWO 128-query subtiles per block: same K/V staging, barriers
// and LDS image as round 8; register-level compute duplicated (A/B query
// sets share K and V fragments). Per-query math/accumulation order is
// unchanged -> bit-identical output.
// ---------------------------------------------------------------------------
__global__ __launch_bounds__(256)
void attn_mfma(const u16* __restrict__ Qbf, const u16* __restrict__ Kbf,
               const u16* __restrict__ Vtg, const float* __restrict__ temp,
               float* __restrict__ Op, float* __restrict__ Rs)
{
    __shared__ __align__(16) u16 ldsKV[2][2][4096];   // [buf][K/V] 8 KB each
    char* L = (char*)ldsKV;

    const int tid  = threadIdx.x;
    const int wid  = tid >> 6;
    const int lane = tid & 63;
    const int hi   = lane >> 5;
    const int ln   = lane & 31;
    const int blk  = blockIdx.x;
    const int sp   = blk & 1;                  // key-range split
    const int qb   = blk >> 1;
    const int bh   = qb / QT256;
    const int qt   = qb - bh * QT256;
    const int b    = bh >> 3, h = bh & 7;
    const int qbA  = qt * 256 + wid * 32;      // subtile A
    const int qbB  = qbA + 128;                // subtile B
    const float mlc = fabsf(temp[h]) * LOG2E;
    const int ktb = sp * 18;                   // [0,18) or [18,37)
    const int kte = sp ? (KT64 + 1) : 18;

    const u16* QrowA = Qbf + ((size_t)bh * NTc + qbA + ln) * Dc;
    const u16* QrowB = Qbf + ((size_t)bh * NTc + qbB + ln) * Dc;
    bf16x8 qfA[4], qfB[4];
#pragma unroll
    for (int ks = 0; ks < 4; ++ks) {
        qfA[ks] = *(const bf16x8*)(QrowA + ks * 16 + hi * 8);
        qfB[ks] = *(const bf16x8*)(QrowB + ks * 16 + hi * 8);
    }

    U4 ones;
    ones.u[0] = ones.u[1] = ones.u[2] = ones.u[3] = 0x3F803F80u;  // bf16 1.0 x8

    f32x16 o0A, o1A, rsA, o0B, o1B, rsB;
#pragma unroll
    for (int r = 0; r < 16; ++r) {
        o0A[r] = 0.f; o1A[r] = 0.f; rsA[r] = 0.f;
        o0B[r] = 0.f; o1B[r] = 0.f; rsB[r] = 0.f;
    }

    const u16* Kbh = Kbf + (size_t)bh * NTc * Dc;
    const u16* Vbh = Vtg + (size_t)bh * Dc * NTc;

    const int sc  = tid & 7;
    const int sr0 = tid >> 3;

#define ATTN_STAGE(BUF, KB)                                                    \
    do {                                                                       \
        char* Kd = L + (BUF) * 16384;                                          \
        char* Vd = Kd + 8192;                                                  \
        _Pragma("unroll")                                                      \
        for (int half_ = 0; half_ < 2; ++half_) {                              \
            const int r_ = sr0 + half_ * 32;                                   \
            const int gc_ = (sc ^ (r_ & 7)) * 8;                               \
            int rK = (KB) + r_;   if (rK > NTc - 1) rK = NTc - 1;              \
            int cV = (KB) + gc_;  if (cV > NTc - 8) cV = NTc - 8;              \
            gll16(Kbh + (size_t)rK * Dc + gc_, Kd + half_ * 4096 + tid * 16);  \
            gll16(Vbh + (size_t)r_ * NTc + cV, Vd + half_ * 4096 + tid * 16);  \
        }                                                                      \
    } while (0)

    ATTN_STAGE(0, ktb * 64);
    __syncthreads();

    for (int kt = ktb; kt < kte; ++kt) {
        const int  cur  = kt & 1;              // ktb even for both splits
        const bool tail = (kt == KT64);
        if (kt + 1 < kte) ATTN_STAGE(cur ^ 1, (kt + 1) * 64);
        const char* Kc = L + cur * 16384;
        const char* Vc = Kc + 8192;

        const int nsub = tail ? 1 : 2;
        for (int kt2 = 0; kt2 < nsub; ++kt2) {
            const int krow = kt2 * 32 + ln;
            const char* kbc = Kc + (krow << 7);
            const int   ksz = (krow & 7) << 4;

            // ---- subtile A: QK^T, softmax, pack ----
            f32x16 s;
#pragma unroll
            for (int r = 0; r < 16; ++r) s[r] = 0.f;
            __builtin_amdgcn_s_setprio(1);
#pragma unroll
            for (int ks = 0; ks < 4; ++ks) {
                const bf16x8 kf = *(const bf16x8*)(kbc + (((ks << 5) + (hi << 4)) ^ ksz));
                s = MFMA32(kf, qfA[ks], s);
            }
            __builtin_amdgcn_s_setprio(0);
            float p[16];
#pragma unroll
            for (int r = 0; r < 16; ++r)
                p[r] = __builtin_amdgcn_exp2f(fmaf(s[r], LOG2E, -mlc));
            if (tail) {
#pragma unroll
                for (int r = 4; r < 16; ++r) p[r] = 0.f;
            }
            u32 a0 = pkb(p[0],  p[1]),  a1 = pkb(p[2],  p[3]);
            u32 b0 = pkb(p[4],  p[5]),  b1 = pkb(p[6],  p[7]);
            u32 c0 = pkb(p[8],  p[9]),  c1 = pkb(p[10], p[11]);
            u32 d0 = pkb(p[12], p[13]), d1 = pkb(p[14], p[15]);
            asm("v_permlane32_swap_b32 %0, %1" : "+v"(a0), "+v"(b0));
            asm("v_permlane32_swap_b32 %0, %1" : "+v"(a1), "+v"(b1));
            asm("v_permlane32_swap_b32 %0, %1" : "+v"(c0), "+v"(d0));
            asm("v_permlane32_swap_b32 %0, %1" : "+v"(c1), "+v"(d1));
            U4 f0A, f1A;
            f0A.u[0] = a0; f0A.u[1] = a1; f0A.u[2] = b0; f0A.u[3] = b1;
            f1A.u[0] = c0; f1A.u[1] = c1; f1A.u[2] = d0; f1A.u[3] = d1;

            // ---- subtile B: QK^T, softmax, pack ----
#pragma unroll
            for (int r = 0; r < 16; ++r) s[r] = 0.f;
            __builtin_amdgcn_s_setprio(1);
#pragma unroll
            for (int ks = 0; ks < 4; ++ks) {
                const bf16x8 kf = *(const bf16x8*)(kbc + (((ks << 5) + (hi << 4)) ^ ksz));
                s = MFMA32(kf, qfB[ks], s);
            }
            __builtin_amdgcn_s_setprio(0);
#pragma unroll
            for (int r = 0; r < 16; ++r)
                p[r] = __builtin_amdgcn_exp2f(fmaf(s[r], LOG2E, -mlc));
            if (tail) {
#pragma unroll
                for (int r = 4; r < 16; ++r) p[r] = 0.f;
            }
            a0 = pkb(p[0],  p[1]);  a1 = pkb(p[2],  p[3]);
            b0 = pkb(p[4],  p[5]);  b1 = pkb(p[6],  p[7]);
            c0 = pkb(p[8],  p[9]);  c1 = pkb(p[10], p[11]);
            d0 = pkb(p[12], p[13]); d1 = pkb(p[14], p[15]);
            asm("v_permlane32_swap_b32 %0, %1" : "+v"(a0), "+v"(b0));
            asm("v_permlane32_swap_b32 %0, %1" : "+v"(a1), "+v"(b1));
            asm("v_permlane32_swap_b32 %0, %1" : "+v"(c0), "+v"(d0));
            asm("v_permlane32_swap_b32 %0, %1" : "+v"(c1), "+v"(d1));
            U4 f0B, f1B;
            f0B.u[0] = a0; f0B.u[1] = a1; f0B.u[2] = b0; f0B.u[3] = b1;
            f1B.u[0] = c0; f1B.u[1] = c1; f1B.u[2] = d0; f1B.u[3] = d1;

            // ---- PV: shared V fragments feed both subtiles ----
            const char* v0c = Vc + (ln << 7);
            const char* v1c = Vc + ((32 + ln) << 7);
            const int   vsz0 = (ln & 7) << 4;
            const int   cof0 = ((kt2 << 6) + (hi << 4)) ^ vsz0;
            const int   cof1 = ((kt2 << 6) + 32 + (hi << 4)) ^ vsz0;
            const bf16x8 vf00 = *(const bf16x8*)(v0c + cof0);
            const bf16x8 vf10 = *(const bf16x8*)(v1c + cof0);
            __builtin_amdgcn_s_setprio(1);
            rsA = MFMA32(ones.f, f0A.f, rsA);
            rsB = MFMA32(ones.f, f0B.f, rsB);
            o0A = MFMA32(vf00, f0A.f, o0A);
            o0B = MFMA32(vf00, f0B.f, o0B);
            o1A = MFMA32(vf10, f0A.f, o1A);
            o1B = MFMA32(vf10, f0B.f, o1B);
            if (!tail) {
                const bf16x8 vf01 = *(const bf16x8*)(v0c + cof1);
                const bf16x8 vf11 = *(const bf16x8*)(v1c + cof1);
                rsA = MFMA32(ones.f, f1A.f, rsA);
                rsB = MFMA32(ones.f, f1B.f, rsB);
                o0A = MFMA32(vf01, f1A.f, o0A);
                o0B = MFMA32(vf01, f1B.f, o0B);
                o1A = MFMA32(vf11, f1A.f, o1A);
                o1B = MFMA32(vf11, f1B.f, o1B);
            }
            __builtin_amdgcn_s_setprio(0);
        }
        __syncthreads();
    }
#undef ATTN_STAGE

    if (hi == 0) {
        Rs[((size_t)sp * 32 + bh) * Nc + qbA + ln] = rsA[0];
        Rs[((size_t)sp * 32 + bh) * Nc + qbB + ln] = rsB[0];
    }

    float* PoA = Op + (size_t)sp * M2c * Cc
                    + ((size_t)b * Nc + qbA + ln) * Cc + h * Dc;
    float* PoB = Op + (size_t)sp * M2c * Cc
                    + ((size_t)b * Nc + qbB + ln) * Cc + h * Dc;
#pragma unroll
    for (int g = 0; g < 4; ++g) {
        *(float4*)(PoA + 8 * g + 4 * hi) =
            make_float4(o0A[4*g], o0A[4*g+1], o0A[4*g+2], o0A[4*g+3]);
        *(float4*)(PoA + 32 + 8 * g + 4 * hi) =
            make_float4(o1A[4*g], o1A[4*g+1], o1A[4*g+2], o1A[4*g+3]);
        *(float4*)(PoB + 8 * g + 4 * hi) =
            make_float4(o0B[4*g], o0B[4*g+1], o0B[4*g+2], o0B[4*g+3]);
        *(float4*)(PoB + 32 + 8 * g + 4 * hi) =
            make_float4(o1B[4*g], o1B[4*g+1], o1B[4*g+2], o1B[4*g+3]);
    }
}

// ---------------------------------------------------------------------------
// Merge split-K partials: O = (Oa+Ob)/(rsa+rsb); emit hi/lo bf16 split.
// ---------------------------------------------------------------------------
__global__ __launch_bounds__(256)
void merge_o(const float* __restrict__ Op, const float* __restrict__ Rs,
             u16* __restrict__ Oh, u16* __restrict__ Ol)
{
    const int id = blockIdx.x * 256 + threadIdx.x;    // 4 floats per thread
    const size_t base = (size_t)id * 4;
    const int row = id >> 7;
    const int c   = (int)(base & 511);
    const int b   = row / Nc, qi = row - b * Nc;
    const int bh  = b * Hc + (c >> 6);
    const float rs = Rs[(size_t)bh * Nc + qi] + Rs[(size_t)(32 + bh) * Nc + qi];
    const float inv = 1.0f / rs;
    const float4 va = *(const float4*)(Op + base);
    const float4 vb = *(const float4*)(Op + (size_t)M2c * Cc + base);
    const float x0 = (va.x + vb.x) * inv, x1 = (va.y + vb.y) * inv;
    const float x2 = (va.z + vb.z) * inv, x3 = (va.w + vb.w) * inv;
    const u32 h0 = f2bf1(x0), h1 = f2bf1(x1), h2 = f2bf1(x2), h3 = f2bf1(x3);
    uint2 hv, lv;
    hv.x = h0 | (h1 << 16);
    hv.y = h2 | (h3 << 16);
    lv.x = pk2(x0 - __uint_as_float(h0 << 16), x1 - __uint_as_float(h1 << 16));
    lv.y = pk2(x2 - __uint_as_float(h2 << 16), x3 - __uint_as_float(h3 << 16));
    *(uint2*)(Oh + base) = hv;
    *(uint2*)(Ol + base) = lv;
}

// ---------------------------------------------------------------------------
extern "C" void kernel_launch(void* const* d_in, const int* in_sizes, int n_in,
                              void* d_out, int out_size, void* d_ws, size_t ws_size,
                              hipStream_t stream)
{
    const float* X    = (const float*)d_in[0];
    const float* S    = (const float*)d_in[1];
    const float* Wqkv = (const float*)d_in[2];
    const float* Wout = (const float*)d_in[3];
    const float* temp = (const float*)d_in[4];
    float* out = (float*)d_out;

    u16* ws16 = (u16*)d_ws;
    const size_t R  = (size_t)M1c * Cc;     // 4,734,976 u16
    const size_t RO = (size_t)M2c * Cc;     // 4,718,592

    // Op region (f32, 2 splits) aliases Abf and Vbf (both dead before attn).
    float* Op  = (float*)ws16;              // 2*RO floats = 4*RO u16
    u16*  Abf  = ws16;                      // [0, R)        in Op region
    u16*  Vbf  = ws16 + R;                  // [R, 2R)       in Op region
    u16*  WqT  = ws16 + 4 * RO;
    u16*  WoTh = WqT  + (size_t)N1c * Cc;
    u16*  WoTl = WoTh + (size_t)Cc * Cc;
    u16*  Qbf  = WoTl + (size_t)Cc * Cc;
    u16*  Kbf  = Qbf + R;
    u16*  Vt   = Kbf + R;
    u16*  Oh   = Vt  + R;
    u16*  Ol   = Oh  + RO;
    float* Rs  = (float*)(Ol + RO);         // 2*32*Nc floats

    // 1) input concat + bf16 cast
    cvt_concat<<<M1c * (Cc / 8) / 256, 256, 0, stream>>>(X, S, Abf);
    // 2) weight transpose-casts
    cvt_w<false><<<dim3(N1c / 64, Cc / 64), 256, 0, stream>>>(Wqkv, N1c, WqT, nullptr);
    cvt_w<true ><<<dim3(Cc  / 64, Cc / 64), 256, 0, stream>>>(Wout, Cc,  WoTh, WoTl);
    // 3) QKV GEMM with fused q/k normalization
    gemm_qkv<<<dim3((M1c + 127) / 128, N1c / 128), 256, 0, stream>>>(Abf, WqT, temp, Qbf, Kbf, Vbf);
    // 4) V transpose -> (B,H,D,Nt)
    transpose_v<<<dim3(Bc * Hc, (NTc + 63) / 64), 256, 0, stream>>>(Vbf, Vt);
    // 5) attention split-K x2, 2 query-subtiles per block -> partials
    attn_mfma<<<Bc * Hc * QT256 * 2, 256, 0, stream>>>(Qbf, Kbf, Vt, temp, Op, Rs);
    // 6) merge partials -> Oattn hi/lo bf16
    merge_o<<<(int)(RO / 4 / 256), 256, 0, stream>>>(Op, Rs, Oh, Ol);
    // 7) out GEMM (split-bf16 3-pass, BK=32 double-buffered) -> f32 out
    gemm_out<<<dim3(M2c / 128, Cc / 64), 256, 0, stream>>>(Oh, Ol, WoTh, WoTl, out);
}

// Round 16
// 172.624 us; speedup vs baseline: 1.0631x; 1.0631x over previous
//
#include <hip/hip_runtime.h>
#include <math.h>

typedef unsigned short u16;
typedef unsigned int   u32;
typedef __attribute__((ext_vector_type(8)))  __bf16 bf16x8;
typedef __attribute__((ext_vector_type(16))) float  f32x16;

constexpr int Bc  = 4;
constexpr int Nc  = 2304;
constexpr int KSc = 8;
constexpr int Cc  = 512;
constexpr int Hc  = 8;
constexpr int Dc  = 64;
constexpr int NTc = Nc + KSc;          // 2312
constexpr int M1c = Bc * NTc;          // 9248
constexpr int N1c = 3 * Cc;            // 1536
constexpr int M2c = Bc * Nc;           // 9216
constexpr int QT128 = Nc / 128;        // 18 query tiles of 128
constexpr int KT64  = NTc / 64;        // 36 full tiles (+8 tail)
constexpr int NSPL  = 3;               // split-K factor
constexpr float LOG2E = 1.4426950408889634f;

__device__ __forceinline__ u32 f2bf1(float f) {
    u32 u = __float_as_uint(f);
    return (u + 0x7fffu + ((u >> 16) & 1u)) >> 16;   // RNE bf16
}
__device__ __forceinline__ u32 pk2(float lo, float hi) {
    u32 ul = __float_as_uint(lo);
    u32 uh = __float_as_uint(hi);
    ul = (ul + 0x7fffu + ((ul >> 16) & 1u)) >> 16;
    uh = (uh + 0x7fffu + ((uh >> 16) & 1u)) & 0xffff0000u;
    return ul | uh;
}
__device__ __forceinline__ float bf2f(u16 x) {
    return __uint_as_float(((u32)x) << 16);
}
__device__ __forceinline__ u32 pkb(float lo, float hi) {
    union { u32 u; __bf16 h[2]; } t;
    t.h[0] = (__bf16)lo; t.h[1] = (__bf16)hi;
    return t.u;
}
// async global->LDS, 16B per lane; LDS dest = wave base + lane*16 (linear)
__device__ __forceinline__ void gll16(const u16* g, char* l) {
    __builtin_amdgcn_global_load_lds(
        (const __attribute__((address_space(1))) unsigned int*)g,
        (__attribute__((address_space(3))) unsigned int*)l, 16, 0, 0);
}

#define MFMA32(A, B, C) __builtin_amdgcn_mfma_f32_32x32x16_bf16(A, B, C, 0, 0, 0)

union U4 { u32 u[4]; bf16x8 f; };

// ---------------------------------------------------------------------------
// concat(X,S) -> bf16 A [M1][512]
// ---------------------------------------------------------------------------
__global__ __launch_bounds__(256)
void cvt_concat(const float* __restrict__ X, const float* __restrict__ S,
                u16* __restrict__ A)
{
    const int id  = blockIdx.x * 256 + threadIdx.x;
    const int row = id >> 6;
    const int ch  = (id & 63) * 8;
    const int b = row / NTc, t = row - b * NTc;
    const float* src = (t < Nc) ? X + ((size_t)(b * Nc + t)) * Cc + ch
                                : S + ((size_t)(b * KSc + (t - Nc))) * Cc + ch;
    const float4 v0 = ((const float4*)src)[0];
    const float4 v1 = ((const float4*)src)[1];
    u32 w[4];
    w[0] = pk2(v0.x, v0.y); w[1] = pk2(v0.z, v0.w);
    w[2] = pk2(v1.x, v1.y); w[3] = pk2(v1.z, v1.w);
    *(uint4*)(A + (size_t)row * Cc + ch) = *(const uint4*)w;
}

// ---------------------------------------------------------------------------
// Transpose-cast weights: W [512][Nn] f32 -> WT [Nn][512] bf16 (+ lo part)
// ---------------------------------------------------------------------------
template<bool LO>
__global__ __launch_bounds__(256)
void cvt_w(const float* __restrict__ W, int Nn,
           u16* __restrict__ WT, u16* __restrict__ WTl)
{
    __shared__ float Ws[64][68];
    const int n0 = blockIdx.x * 64, k0 = blockIdx.y * 64;
#pragma unroll
    for (int i = 0; i < 4; ++i) {
        const int c = i * 256 + threadIdx.x;
        const int kr = c >> 4, nc = (c & 15) * 4;
        const float4 v = *(const float4*)(W + (size_t)(k0 + kr) * Nn + n0 + nc);
        Ws[kr][nc] = v.x; Ws[kr][nc+1] = v.y; Ws[kr][nc+2] = v.z; Ws[kr][nc+3] = v.w;
    }
    __syncthreads();
#pragma unroll
    for (int i = 0; i < 2; ++i) {
        const int c = i * 256 + threadIdx.x;
        const int n = c >> 3, kc = (c & 7) * 8;
        u32 wh[4], wl[4];
#pragma unroll
        for (int j = 0; j < 4; ++j) {
            const float a = Ws[kc + 2*j][n], bq = Ws[kc + 2*j + 1][n];
            const u32 ha = f2bf1(a), hb = f2bf1(bq);
            wh[j] = ha | (hb << 16);
            if constexpr (LO) {
                const float la = a  - __uint_as_float(ha << 16);
                const float lb = bq - __uint_as_float(hb << 16);
                wl[j] = pk2(la, lb);
            }
        }
        *(uint4*)(WT + (size_t)(n0 + n) * Cc + k0 + kc) = *(const uint4*)wh;
        if constexpr (LO)
            *(uint4*)(WTl + (size_t)(n0 + n) * Cc + k0 + kc) = *(const uint4*)wl;
    }
}

// ---------------------------------------------------------------------------
// V (B,H,Nt,D) bf16 -> Vt (B,H,D,Nt) bf16
// ---------------------------------------------------------------------------
__global__ __launch_bounds__(256)
void transpose_v(const u16* __restrict__ Vbf, u16* __restrict__ Vt)
{
    __shared__ u16 Vs[64][80];
    const int bh = blockIdx.x;
    const int t0 = blockIdx.y * 64;
    const u16* src = Vbf + (size_t)bh * NTc * Dc;
#pragma unroll
    for (int i = 0; i < 2; ++i) {
        const int c = i * 256 + threadIdx.x;
        const int tr = c >> 3, dc = (c & 7) * 8;
        int tg = t0 + tr; if (tg > NTc - 1) tg = NTc - 1;
        const uint4 v = *(const uint4*)(src + (size_t)tg * Dc + dc);
        *(uint4*)&Vs[tr][dc] = v;
    }
    __syncthreads();
#pragma unroll
    for (int i = 0; i < 2; ++i) {
        const int c = i * 256 + threadIdx.x;
        const int d = c >> 3, tch = (c & 7) * 8;
        if (t0 + tch + 7 <= NTc - 1) {
            u16 tmp[8];
#pragma unroll
            for (int j = 0; j < 8; ++j) tmp[j] = Vs[tch + j][d];
            *(uint4*)(Vt + ((size_t)bh * Dc + d) * NTc + t0 + tch) = *(const uint4*)tmp;
        }
    }
}

// ---------------------------------------------------------------------------
// QKV GEMM, bf16 MFMA, global_load_lds double-buffered staging.
// Fused q/k L2-norm epilogue (round-14 verified).
// ---------------------------------------------------------------------------
__global__ __launch_bounds__(256)
void gemm_qkv(const u16* __restrict__ A, const u16* __restrict__ Bw,
              const float* __restrict__ temp,
              u16* __restrict__ Qb, u16* __restrict__ Kb, u16* __restrict__ Vb)
{
    __shared__ __align__(16) u16 lds[2 * 2 * 8192];   // [buf][A/B] 16 KB each
    char* L = (char*)lds;

    const int tid = threadIdx.x;
    const int wid = tid >> 6, lane = tid & 63, hi = lane >> 5, ln = lane & 31;
    const int wm = wid >> 1, wn = wid & 1;
    const int m0 = blockIdx.x * 128, n0 = blockIdx.y * 128;

    const int sr = tid >> 3;
    const int sc = tid & 7;

    f32x16 acc[2][2];
#pragma unroll
    for (int i = 0; i < 2; ++i)
#pragma unroll
        for (int j = 0; j < 2; ++j)
#pragma unroll
            for (int r = 0; r < 16; ++r) acc[i][j][r] = 0.f;

#define QKV_STAGE(BUF, K0)                                                     \
    do {                                                                       \
        char* dA = L + (BUF) * 32768;                                          \
        char* dB = dA + 16384;                                                 \
        _Pragma("unroll")                                                      \
        for (int i_ = 0; i_ < 4; ++i_) {                                       \
            const int row_ = i_ * 32 + sr;                                     \
            const int gc_  = (sc ^ (row_ & 7)) * 8;                            \
            int mg_ = m0 + row_; if (mg_ > M1c - 1) mg_ = M1c - 1;             \
            gll16(A  + (size_t)mg_ * Cc + (K0) + gc_,                          \
                  dA + i_ * 4096 + tid * 16);                                  \
            gll16(Bw + (size_t)(n0 + row_) * Cc + (K0) + gc_,                  \
                  dB + i_ * 4096 + tid * 16);                                  \
        }                                                                      \
    } while (0)

    QKV_STAGE(0, 0);
    __syncthreads();

    for (int k0 = 0; k0 < Cc; k0 += 64) {
        const int cur = (k0 >> 6) & 1;
        if (k0 + 64 < Cc) QKV_STAGE(cur ^ 1, k0 + 64);
        const char* ldsA = L + cur * 32768;
        const char* ldsB = ldsA + 16384;
#pragma unroll
        for (int ks = 0; ks < 4; ++ks) {
            bf16x8 af[2], bfr[2];
#pragma unroll
            for (int f = 0; f < 2; ++f) {
                const int mr = wm * 64 + f * 32 + ln;
                af[f]  = *(const bf16x8*)(ldsA + mr * 128 + (((ks * 2 + hi) ^ (mr & 7)) << 4));
                const int nr = wn * 64 + f * 32 + ln;
                bfr[f] = *(const bf16x8*)(ldsB + nr * 128 + (((ks * 2 + hi) ^ (nr & 7)) << 4));
            }
#pragma unroll
            for (int fm = 0; fm < 2; ++fm)
#pragma unroll
                for (int fn = 0; fn < 2; ++fn)
                    acc[fm][fn] = MFMA32(af[fm], bfr[fn], acc[fm][fn]);
        }
        __syncthreads();
    }
#undef QKV_STAGE

    const int which = n0 >> 9;
    const int hh = ((n0 + wn * 64) >> 6) & 7;

    if (which < 2) {
        const float tsc = (which == 0) ? temp[hh] : 1.0f;
#pragma unroll
        for (int fm = 0; fm < 2; ++fm)
#pragma unroll
            for (int r = 0; r < 16; ++r) {
                float ss = fmaf(acc[fm][0][r], acc[fm][0][r],
                                acc[fm][1][r] * acc[fm][1][r]);
                ss += __shfl_xor(ss, 1);
                ss += __shfl_xor(ss, 2);
                ss += __shfl_xor(ss, 4);
                ss += __shfl_xor(ss, 8);
                ss += __shfl_xor(ss, 16);
                const float scl = tsc / fmaxf(sqrtf(ss), 1e-12f);
                acc[fm][0][r] *= scl;
                acc[fm][1][r] *= scl;
            }
    }

#pragma unroll
    for (int fm = 0; fm < 2; ++fm)
#pragma unroll
        for (int fn = 0; fn < 2; ++fn) {
            const int ng = n0 + wn * 64 + fn * 32 + ln;
            const int h = (ng >> 6) & 7, d = ng & 63;
            u16* base = (which == 0) ? Qb : ((which == 1) ? Kb : Vb);
#pragma unroll
            for (int r = 0; r < 16; ++r) {
                const int mg = m0 + wm * 64 + fm * 32 + (r & 3) + 8 * (r >> 2) + 4 * hi;
                if (mg < M1c) {
                    const int b = mg / NTc, t = mg - b * NTc;
                    base[((size_t)((b * Hc + h) * NTc + t)) * Dc + d] = (u16)f2bf1(acc[fm][fn][r]);
                }
            }
        }
}

// ---------------------------------------------------------------------------
// Out GEMM, split-bf16 3-pass, BK=32 double-buffered global_load_lds staging.
// ---------------------------------------------------------------------------
__global__ __launch_bounds__(256)
void gemm_out(const u16* __restrict__ Ahg, const u16* __restrict__ Alg,
              const u16* __restrict__ Bhg, const u16* __restrict__ Blg,
              float* __restrict__ Out)
{
    __shared__ __align__(16) u16 lds[2 * 12288];      // 2 x 24 KB
    char* L = (char*)lds;

    const int tid = threadIdx.x;
    const int wid = tid >> 6, lane = tid & 63, hi = lane >> 5, ln = lane & 31;
    const int wm = wid >> 1, wn = wid & 1;
    const int m0 = blockIdx.x * 128, n0 = blockIdx.y * 64;
    const int sr2 = tid >> 2;
    const int sc2 = tid & 3;

    f32x16 acc[2];
#pragma unroll
    for (int i = 0; i < 2; ++i)
#pragma unroll
        for (int r = 0; r < 16; ++r) acc[i][r] = 0.f;

#define OUT_STAGE(BUF, K0)                                                     \
    do {                                                                       \
        char* bb = L + (BUF) * 24576;                                          \
        _Pragma("unroll")                                                      \
        for (int i_ = 0; i_ < 2; ++i_) {                                       \
            const int row_ = i_ * 64 + sr2;                                    \
            const int gc_  = (sc2 ^ (row_ & 3)) * 8;                           \
            const size_t go_ = (size_t)(m0 + row_) * Cc + (K0) + gc_;          \
            gll16(Ahg + go_, bb + i_ * 4096 + tid * 16);                       \
            gll16(Alg + go_, bb + 8192 + i_ * 4096 + tid * 16);                \
        }                                                                      \
        {                                                                      \
            const int gc_  = (sc2 ^ (sr2 & 3)) * 8;                            \
            const size_t go_ = (size_t)(n0 + sr2) * Cc + (K0) + gc_;           \
            gll16(Bhg + go_, bb + 16384 + tid * 16);                           \
            gll16(Blg + go_, bb + 20480 + tid * 16);                           \
        }                                                                      \
    } while (0)

    OUT_STAGE(0, 0);
    __syncthreads();

    for (int k0 = 0; k0 < Cc; k0 += 32) {
        const int cur = (k0 >> 5) & 1;
        if (k0 + 32 < Cc) OUT_STAGE(cur ^ 1, k0 + 32);
        const char* bb = L + cur * 24576;
        const char* pAh = bb;
        const char* pAl = bb + 8192;
        const char* pBh = bb + 16384;
        const char* pBl = bb + 20480;
#pragma unroll
        for (int ks = 0; ks < 2; ++ks) {
            bf16x8 afh[2], afl[2], bfh, bfl;
#pragma unroll
            for (int f = 0; f < 2; ++f) {
                const int mr = wm * 64 + f * 32 + ln;
                const int moff = mr * 64 + (((ks * 2 + hi) ^ (mr & 3)) << 4);
                afh[f] = *(const bf16x8*)(pAh + moff);
                afl[f] = *(const bf16x8*)(pAl + moff);
            }
            {
                const int nr = wn * 32 + ln;
                const int noff = nr * 64 + (((ks * 2 + hi) ^ (nr & 3)) << 4);
                bfh = *(const bf16x8*)(pBh + noff);
                bfl = *(const bf16x8*)(pBl + noff);
            }
#pragma unroll
            for (int fm = 0; fm < 2; ++fm) {
                acc[fm] = MFMA32(afh[fm], bfh, acc[fm]);
                acc[fm] = MFMA32(afl[fm], bfh, acc[fm]);
                acc[fm] = MFMA32(afh[fm], bfl, acc[fm]);
            }
        }
        __syncthreads();
    }
#undef OUT_STAGE

#pragma unroll
    for (int fm = 0; fm < 2; ++fm) {
        const int ng = n0 + wn * 32 + ln;
#pragma unroll
        for (int r = 0; r < 16; ++r) {
            const int mg = m0 + wm * 64 + fm * 32 + (r & 3) + 8 * (r >> 2) + 4 * hi;
            Out[(size_t)mg * Cc + ng] = acc[fm][r];
        }
    }
}

// ---------------------------------------------------------------------------
// MFMA flash attention, split-K x3, 4 waves x 32 queries (128 q/block).
// FROZEN round-12 register structure (VGPR 64). Buffer parity is relative
// (cur = (kt-ktb)&1) so any ktb works. Key splits: [0,13) [13,26) [26,37).
// ---------------------------------------------------------------------------
__global__ __launch_bounds__(256)
void attn_mfma(const u16* __restrict__ Qbf, const u16* __restrict__ Kbf,
               const u16* __restrict__ Vtg, const float* __restrict__ temp,
               float* __restrict__ Op, float* __restrict__ Rs)
{
    __shared__ __align__(16) u16 ldsKV[2][2][4096];   // [buf][K/V] 8 KB each
    char* L = (char*)ldsKV;

    const int tid  = threadIdx.x;
    const int wid  = tid >> 6;
    const int lane = tid & 63;
    const int hi   = lane >> 5;
    const int ln   = lane & 31;
    const int blk  = blockIdx.x;
    const int sp   = blk % NSPL;               // key-range split 0..2
    const int qb   = blk / NSPL;
    const int bh   = qb / QT128;
    const int qt   = qb - bh * QT128;
    const int b    = bh >> 3, h = bh & 7;
    const int qbase = qt * 128 + wid * 32;
    const float mlc = fabsf(temp[h]) * LOG2E;
    const int ktb = (sp == 0) ? 0 : (sp == 1 ? 13 : 26);
    const int kte = (sp == 0) ? 13 : (sp == 1 ? 26 : (KT64 + 1));

    const u16* Qrow = Qbf + ((size_t)bh * NTc + qbase + ln) * Dc;
    bf16x8 qf[4];
#pragma unroll
    for (int ks = 0; ks < 4; ++ks)
        qf[ks] = *(const bf16x8*)(Qrow + ks * 16 + hi * 8);

    U4 ones;
    ones.u[0] = ones.u[1] = ones.u[2] = ones.u[3] = 0x3F803F80u;  // bf16 1.0 x8

    f32x16 o0, o1, rsacc;
#pragma unroll
    for (int r = 0; r < 16; ++r) { o0[r] = 0.f; o1[r] = 0.f; rsacc[r] = 0.f; }

    const u16* Kbh = Kbf + (size_t)bh * NTc * Dc;
    const u16* Vbh = Vtg + (size_t)bh * Dc * NTc;

    const int sc  = tid & 7;
    const int sr0 = tid >> 3;

#define ATTN_STAGE(BUF, KB)                                                    \
    do {                                                                       \
        char* Kd = L + (BUF) * 16384;                                          \
        char* Vd = Kd + 8192;                                                  \
        _Pragma("unroll")                                                      \
        for (int half_ = 0; half_ < 2; ++half_) {                              \
            const int r_ = sr0 + half_ * 32;                                   \
            const int gc_ = (sc ^ (r_ & 7)) * 8;                               \
            int rK = (KB) + r_;   if (rK > NTc - 1) rK = NTc - 1;              \
            int cV = (KB) + gc_;  if (cV > NTc - 8) cV = NTc - 8;              \
            gll16(Kbh + (size_t)rK * Dc + gc_, Kd + half_ * 4096 + tid * 16);  \
            gll16(Vbh + (size_t)r_ * NTc + cV, Vd + half_ * 4096 + tid * 16);  \
        }                                                                      \
    } while (0)

    ATTN_STAGE(0, ktb * 64);
    __syncthreads();

    for (int kt = ktb; kt < kte; ++kt) {
        const int  cur  = (kt - ktb) & 1;      // relative parity: any ktb
        const bool tail = (kt == KT64);
        if (kt + 1 < kte) ATTN_STAGE(cur ^ 1, (kt + 1) * 64);
        const char* Kc = L + cur * 16384;
        const char* Vc = Kc + 8192;

        const int nsub = tail ? 1 : 2;
        for (int kt2 = 0; kt2 < nsub; ++kt2) {
            f32x16 s;
#pragma unroll
            for (int r = 0; r < 16; ++r) s[r] = 0.f;
            const int krow = kt2 * 32 + ln;
            const char* kbc = Kc + (krow << 7);
            const int   ksz = (krow & 7) << 4;
            __builtin_amdgcn_s_setprio(1);
#pragma unroll
            for (int ks = 0; ks < 4; ++ks) {
                const bf16x8 kf = *(const bf16x8*)(kbc + (((ks << 5) + (hi << 4)) ^ ksz));
                s = MFMA32(kf, qf[ks], s);
            }
            __builtin_amdgcn_s_setprio(0);

            float p[16];
#pragma unroll
            for (int r = 0; r < 16; ++r)
                p[r] = __builtin_amdgcn_exp2f(fmaf(s[r], LOG2E, -mlc));
            if (tail) {
#pragma unroll
                for (int r = 4; r < 16; ++r) p[r] = 0.f;   // keys >= 8 invalid
            }

            u32 a0 = pkb(p[0],  p[1]),  a1 = pkb(p[2],  p[3]);
            u32 b0 = pkb(p[4],  p[5]),  b1 = pkb(p[6],  p[7]);
            u32 c0 = pkb(p[8],  p[9]),  c1 = pkb(p[10], p[11]);
            u32 d0 = pkb(p[12], p[13]), d1 = pkb(p[14], p[15]);
            asm("v_permlane32_swap_b32 %0, %1" : "+v"(a0), "+v"(b0));
            asm("v_permlane32_swap_b32 %0, %1" : "+v"(a1), "+v"(b1));
            asm("v_permlane32_swap_b32 %0, %1" : "+v"(c0), "+v"(d0));
            asm("v_permlane32_swap_b32 %0, %1" : "+v"(c1), "+v"(d1));
            U4 f0, f1;
            f0.u[0] = a0; f0.u[1] = a1; f0.u[2] = b0; f0.u[3] = b1;
            f1.u[0] = c0; f1.u[1] = c1; f1.u[2] = d0; f1.u[3] = d1;

            const char* v0c = Vc + (ln << 7);
            const char* v1c = Vc + ((32 + ln) << 7);
            const int   vsz0 = (ln & 7) << 4;
            const int   cof0 = ((kt2 << 6) + (hi << 4)) ^ vsz0;
            const int   cof1 = ((kt2 << 6) + 32 + (hi << 4)) ^ vsz0;
            __builtin_amdgcn_s_setprio(1);
            rsacc = MFMA32(ones.f, f0.f, rsacc);
            o0 = MFMA32(*(const bf16x8*)(v0c + cof0), f0.f, o0);
            o1 = MFMA32(*(const bf16x8*)(v1c + cof0), f0.f, o1);
            if (!tail) {
                rsacc = MFMA32(ones.f, f1.f, rsacc);
                o0 = MFMA32(*(const bf16x8*)(v0c + cof1), f1.f, o0);
                o1 = MFMA32(*(const bf16x8*)(v1c + cof1), f1.f, o1);
            }
            __builtin_amdgcn_s_setprio(0);
        }
        __syncthreads();
    }
#undef ATTN_STAGE

    if (hi == 0)
        Rs[((size_t)sp * 32 + bh) * Nc + qbase + ln] = rsacc[0];

    float* Po = Op + (size_t)sp * M2c * Cc
                   + ((size_t)b * Nc + qbase + ln) * Cc + h * Dc;
#pragma unroll
    for (int g = 0; g < 4; ++g) {
        *(float4*)(Po + 8 * g + 4 * hi) =
            make_float4(o0[4*g], o0[4*g+1], o0[4*g+2], o0[4*g+3]);
        *(float4*)(Po + 32 + 8 * g + 4 * hi) =
            make_float4(o1[4*g], o1[4*g+1], o1[4*g+2], o1[4*g+3]);
    }
}

// ---------------------------------------------------------------------------
// Merge split-K x3 partials: O = (Oa+Ob+Oc)/(rsa+rsb+rsc); hi/lo bf16 out.
// ---------------------------------------------------------------------------
__global__ __launch_bounds__(256)
void merge_o(const float* __restrict__ Op, const float* __restrict__ Rs,
             u16* __restrict__ Oh, u16* __restrict__ Ol)
{
    const int id = blockIdx.x * 256 + threadIdx.x;    // 4 floats per thread
    const size_t base = (size_t)id * 4;
    const int row = id >> 7;
    const int c   = (int)(base & 511);
    const int b   = row / Nc, qi = row - b * Nc;
    const int bh  = b * Hc + (c >> 6);
    const float rs = Rs[(size_t)bh * Nc + qi]
                   + Rs[(size_t)(32 + bh) * Nc + qi]
                   + Rs[(size_t)(64 + bh) * Nc + qi];
    const float inv = 1.0f / rs;
    const float4 va = *(const float4*)(Op + base);
    const float4 vb = *(const float4*)(Op + (size_t)M2c * Cc + base);
    const float4 vc = *(const float4*)(Op + 2 * (size_t)M2c * Cc + base);
    const float x0 = (va.x + vb.x + vc.x) * inv, x1 = (va.y + vb.y + vc.y) * inv;
    const float x2 = (va.z + vb.z + vc.z) * inv, x3 = (va.w + vb.w + vc.w) * inv;
    const u32 h0 = f2bf1(x0), h1 = f2bf1(x1), h2 = f2bf1(x2), h3 = f2bf1(x3);
    uint2 hv, lv;
    hv.x = h0 | (h1 << 16);
    hv.y = h2 | (h3 << 16);
    lv.x = pk2(x0 - __uint_as_float(h0 << 16), x1 - __uint_as_float(h1 << 16));
    lv.y = pk2(x2 - __uint_as_float(h2 << 16), x3 - __uint_as_float(h3 << 16));
    *(uint2*)(Oh + base) = hv;
    *(uint2*)(Ol + base) = lv;
}

// ---------------------------------------------------------------------------
extern "C" void kernel_launch(void* const* d_in, const int* in_sizes, int n_in,
                              void* d_out, int out_size, void* d_ws, size_t ws_size,
                              hipStream_t stream)
{
    const float* X    = (const float*)d_in[0];
    const float* S    = (const float*)d_in[1];
    const float* Wqkv = (const float*)d_in[2];
    const float* Wout = (const float*)d_in[3];
    const float* temp = (const float*)d_in[4];
    float* out = (float*)d_out;

    u16* ws16 = (u16*)d_ws;
    const size_t R  = (size_t)M1c * Cc;     // 4,734,976 u16
    const size_t RO = (size_t)M2c * Cc;     // 4,718,592

    // Op region: 3 x RO f32 = 6*RO u16, aliasing Abf, Vbf, WqT (all dead
    // before attn writes Op).
    float* Op  = (float*)ws16;
    u16*  Abf  = ws16;                      // [0, R)
    u16*  Vbf  = ws16 + R;                  // [R, 2R)
    u16*  WqT  = ws16 + 2 * R;              // [2R, 2R+N1c*Cc)  << 6*RO
    u16*  WoTh = ws16 + 6 * RO;
    u16*  WoTl = WoTh + (size_t)Cc * Cc;
    u16*  Qbf  = WoTl + (size_t)Cc * Cc;
    u16*  Kbf  = Qbf + R;
    u16*  Vt   = Kbf + R;
    float* Rs  = (float*)(Vt + R);          // NSPL*32*Nc floats
    u16*  Oh   = Qbf;                       // alias: Qbf dead after attn
    u16*  Ol   = Kbf;                       // alias: Kbf dead after attn

    // 1) input concat + bf16 cast
    cvt_concat<<<M1c * (Cc / 8) / 256, 256, 0, stream>>>(X, S, Abf);
    // 2) weight transpose-casts
    cvt_w<false><<<dim3(N1c / 64, Cc / 64), 256, 0, stream>>>(Wqkv, N1c, WqT, nullptr);
    cvt_w<true ><<<dim3(Cc  / 64, Cc / 64), 256, 0, stream>>>(Wout, Cc,  WoTh, WoTl);
    // 3) QKV GEMM with fused q/k normalization
    gemm_qkv<<<dim3((M1c + 127) / 128, N1c / 128), 256, 0, stream>>>(Abf, WqT, temp, Qbf, Kbf, Vbf);
    // 4) V transpose -> (B,H,D,Nt)
    transpose_v<<<dim3(Bc * Hc, (NTc + 63) / 64), 256, 0, stream>>>(Vbf, Vt);
    // 5) attention split-K x3 (4-wave/128q, frozen core) -> partials
    attn_mfma<<<Bc * Hc * QT128 * NSPL, 256, 0, stream>>>(Qbf, Kbf, Vt, temp, Op, Rs);
    // 6) merge partials -> Oattn hi/lo bf16 (aliases dead Qbf/Kbf)
    merge_o<<<(int)(RO / 4 / 256), 256, 0, stream>>>(Op, Rs, Oh, Ol);
    // 7) out GEMM (split-bf16 3-pass, BK=32 double-buffered) -> f32 out
    gemm_out<<<dim3(M2c / 128, Cc / 64), 256, 0, stream>>>(Oh, Ol, WoTh, WoTl, out);
}

// Round 17
// 170.587 us; speedup vs baseline: 1.0758x; 1.0119x over previous
//
#include <hip/hip_runtime.h>
#include <math.h>

typedef unsigned short u16;
typedef unsigned int   u32;
typedef __attribute__((ext_vector_type(8)))  __bf16 bf16x8;
typedef __attribute__((ext_vector_type(16))) float  f32x16;

constexpr int Bc  = 4;
constexpr int Nc  = 2304;
constexpr int KSc = 8;
constexpr int Cc  = 512;
constexpr int Hc  = 8;
constexpr int Dc  = 64;
constexpr int NTc = Nc + KSc;          // 2312
constexpr int M1c = Bc * NTc;          // 9248
constexpr int N1c = 3 * Cc;            // 1536
constexpr int M2c = Bc * Nc;           // 9216
constexpr int QT128 = Nc / 128;        // 18 query tiles of 128
constexpr int KT64  = NTc / 64;        // 36 full tiles (+8 tail)
constexpr int NSPL  = 3;               // split-K factor
constexpr float LOG2E = 1.4426950408889634f;

__device__ __forceinline__ u32 f2bf1(float f) {
    u32 u = __float_as_uint(f);
    return (u + 0x7fffu + ((u >> 16) & 1u)) >> 16;   // RNE bf16
}
__device__ __forceinline__ u32 pk2(float lo, float hi) {
    u32 ul = __float_as_uint(lo);
    u32 uh = __float_as_uint(hi);
    ul = (ul + 0x7fffu + ((ul >> 16) & 1u)) >> 16;
    uh = (uh + 0x7fffu + ((uh >> 16) & 1u)) & 0xffff0000u;
    return ul | uh;
}
__device__ __forceinline__ float bf2f(u16 x) {
    return __uint_as_float(((u32)x) << 16);
}
__device__ __forceinline__ u32 pkb(float lo, float hi) {
    union { u32 u; __bf16 h[2]; } t;
    t.h[0] = (__bf16)lo; t.h[1] = (__bf16)hi;
    return t.u;
}
// async global->LDS, 16B per lane; LDS dest = wave base + lane*16 (linear)
__device__ __forceinline__ void gll16(const u16* g, char* l) {
    __builtin_amdgcn_global_load_lds(
        (const __attribute__((address_space(1))) unsigned int*)g,
        (__attribute__((address_space(3))) unsigned int*)l, 16, 0, 0);
}

#define MFMA32(A, B, C) __builtin_amdgcn_mfma_f32_32x32x16_bf16(A, B, C, 0, 0, 0)

union U4 { u32 u[4]; bf16x8 f; };

// ---------------------------------------------------------------------------
// concat(X,S) -> bf16 A [M1][512]
// ---------------------------------------------------------------------------
__global__ __launch_bounds__(256)
void cvt_concat(const float* __restrict__ X, const float* __restrict__ S,
                u16* __restrict__ A)
{
    const int id  = blockIdx.x * 256 + threadIdx.x;
    const int row = id >> 6;
    const int ch  = (id & 63) * 8;
    const int b = row / NTc, t = row - b * NTc;
    const float* src = (t < Nc) ? X + ((size_t)(b * Nc + t)) * Cc + ch
                                : S + ((size_t)(b * KSc + (t - Nc))) * Cc + ch;
    const float4 v0 = ((const float4*)src)[0];
    const float4 v1 = ((const float4*)src)[1];
    u32 w[4];
    w[0] = pk2(v0.x, v0.y); w[1] = pk2(v0.z, v0.w);
    w[2] = pk2(v1.x, v1.y); w[3] = pk2(v1.z, v1.w);
    *(uint4*)(A + (size_t)row * Cc + ch) = *(const uint4*)w;
}

// ---------------------------------------------------------------------------
// Transpose-cast weights: W [512][Nn] f32 -> WT [Nn][512] bf16 (+ lo part)
// ---------------------------------------------------------------------------
template<bool LO>
__global__ __launch_bounds__(256)
void cvt_w(const float* __restrict__ W, int Nn,
           u16* __restrict__ WT, u16* __restrict__ WTl)
{
    __shared__ float Ws[64][68];
    const int n0 = blockIdx.x * 64, k0 = blockIdx.y * 64;
#pragma unroll
    for (int i = 0; i < 4; ++i) {
        const int c = i * 256 + threadIdx.x;
        const int kr = c >> 4, nc = (c & 15) * 4;
        const float4 v = *(const float4*)(W + (size_t)(k0 + kr) * Nn + n0 + nc);
        Ws[kr][nc] = v.x; Ws[kr][nc+1] = v.y; Ws[kr][nc+2] = v.z; Ws[kr][nc+3] = v.w;
    }
    __syncthreads();
#pragma unroll
    for (int i = 0; i < 2; ++i) {
        const int c = i * 256 + threadIdx.x;
        const int n = c >> 3, kc = (c & 7) * 8;
        u32 wh[4], wl[4];
#pragma unroll
        for (int j = 0; j < 4; ++j) {
            const float a = Ws[kc + 2*j][n], bq = Ws[kc + 2*j + 1][n];
            const u32 ha = f2bf1(a), hb = f2bf1(bq);
            wh[j] = ha | (hb << 16);
            if constexpr (LO) {
                const float la = a  - __uint_as_float(ha << 16);
                const float lb = bq - __uint_as_float(hb << 16);
                wl[j] = pk2(la, lb);
            }
        }
        *(uint4*)(WT + (size_t)(n0 + n) * Cc + k0 + kc) = *(const uint4*)wh;
        if constexpr (LO)
            *(uint4*)(WTl + (size_t)(n0 + n) * Cc + k0 + kc) = *(const uint4*)wl;
    }
}

// ---------------------------------------------------------------------------
// V (B,H,Nt,D) bf16 -> Vt (B,H,D,Nt) bf16
// ---------------------------------------------------------------------------
__global__ __launch_bounds__(256)
void transpose_v(const u16* __restrict__ Vbf, u16* __restrict__ Vt)
{
    __shared__ u16 Vs[64][80];
    const int bh = blockIdx.x;
    const int t0 = blockIdx.y * 64;
    const u16* src = Vbf + (size_t)bh * NTc * Dc;
#pragma unroll
    for (int i = 0; i < 2; ++i) {
        const int c = i * 256 + threadIdx.x;
        const int tr = c >> 3, dc = (c & 7) * 8;
        int tg = t0 + tr; if (tg > NTc - 1) tg = NTc - 1;
        const uint4 v = *(const uint4*)(src + (size_t)tg * Dc + dc);
        *(uint4*)&Vs[tr][dc] = v;
    }
    __syncthreads();
#pragma unroll
    for (int i = 0; i < 2; ++i) {
        const int c = i * 256 + threadIdx.x;
        const int d = c >> 3, tch = (c & 7) * 8;
        if (t0 + tch + 7 <= NTc - 1) {
            u16 tmp[8];
#pragma unroll
            for (int j = 0; j < 8; ++j) tmp[j] = Vs[tch + j][d];
            *(uint4*)(Vt + ((size_t)bh * Dc + d) * NTc + t0 + tch) = *(const uint4*)tmp;
        }
    }
}

// ---------------------------------------------------------------------------
// QKV GEMM, bf16 MFMA, global_load_lds double-buffered staging.
// Fused q/k L2-norm epilogue.
// ---------------------------------------------------------------------------
__global__ __launch_bounds__(256)
void gemm_qkv(const u16* __restrict__ A, const u16* __restrict__ Bw,
              const float* __restrict__ temp,
              u16* __restrict__ Qb, u16* __restrict__ Kb, u16* __restrict__ Vb)
{
    __shared__ __align__(16) u16 lds[2 * 2 * 8192];   // [buf][A/B] 16 KB each
    char* L = (char*)lds;

    const int tid = threadIdx.x;
    const int wid = tid >> 6, lane = tid & 63, hi = lane >> 5, ln = lane & 31;
    const int wm = wid >> 1, wn = wid & 1;
    const int m0 = blockIdx.x * 128, n0 = blockIdx.y * 128;

    const int sr = tid >> 3;
    const int sc = tid & 7;

    f32x16 acc[2][2];
#pragma unroll
    for (int i = 0; i < 2; ++i)
#pragma unroll
        for (int j = 0; j < 2; ++j)
#pragma unroll
            for (int r = 0; r < 16; ++r) acc[i][j][r] = 0.f;

#define QKV_STAGE(BUF, K0)                                                     \
    do {                                                                       \
        char* dA = L + (BUF) * 32768;                                          \
        char* dB = dA + 16384;                                                 \
        _Pragma("unroll")                                                      \
        for (int i_ = 0; i_ < 4; ++i_) {                                       \
            const int row_ = i_ * 32 + sr;                                     \
            const int gc_  = (sc ^ (row_ & 7)) * 8;                            \
            int mg_ = m0 + row_; if (mg_ > M1c - 1) mg_ = M1c - 1;             \
            gll16(A  + (size_t)mg_ * Cc + (K0) + gc_,                          \
                  dA + i_ * 4096 + tid * 16);                                  \
            gll16(Bw + (size_t)(n0 + row_) * Cc + (K0) + gc_,                  \
                  dB + i_ * 4096 + tid * 16);                                  \
        }                                                                      \
    } while (0)

    QKV_STAGE(0, 0);
    __syncthreads();

    for (int k0 = 0; k0 < Cc; k0 += 64) {
        const int cur = (k0 >> 6) & 1;
        if (k0 + 64 < Cc) QKV_STAGE(cur ^ 1, k0 + 64);
        const char* ldsA = L + cur * 32768;
        const char* ldsB = ldsA + 16384;
#pragma unroll
        for (int ks = 0; ks < 4; ++ks) {
            bf16x8 af[2], bfr[2];
#pragma unroll
            for (int f = 0; f < 2; ++f) {
                const int mr = wm * 64 + f * 32 + ln;
                af[f]  = *(const bf16x8*)(ldsA + mr * 128 + (((ks * 2 + hi) ^ (mr & 7)) << 4));
                const int nr = wn * 64 + f * 32 + ln;
                bfr[f] = *(const bf16x8*)(ldsB + nr * 128 + (((ks * 2 + hi) ^ (nr & 7)) << 4));
            }
#pragma unroll
            for (int fm = 0; fm < 2; ++fm)
#pragma unroll
                for (int fn = 0; fn < 2; ++fn)
                    acc[fm][fn] = MFMA32(af[fm], bfr[fn], acc[fm][fn]);
        }
        __syncthreads();
    }
#undef QKV_STAGE

    const int which = n0 >> 9;
    const int hh = ((n0 + wn * 64) >> 6) & 7;

    if (which < 2) {
        const float tsc = (which == 0) ? temp[hh] : 1.0f;
#pragma unroll
        for (int fm = 0; fm < 2; ++fm)
#pragma unroll
            for (int r = 0; r < 16; ++r) {
                float ss = fmaf(acc[fm][0][r], acc[fm][0][r],
                                acc[fm][1][r] * acc[fm][1][r]);
                ss += __shfl_xor(ss, 1);
                ss += __shfl_xor(ss, 2);
                ss += __shfl_xor(ss, 4);
                ss += __shfl_xor(ss, 8);
                ss += __shfl_xor(ss, 16);
                const float scl = tsc / fmaxf(sqrtf(ss), 1e-12f);
                acc[fm][0][r] *= scl;
                acc[fm][1][r] *= scl;
            }
    }

#pragma unroll
    for (int fm = 0; fm < 2; ++fm)
#pragma unroll
        for (int fn = 0; fn < 2; ++fn) {
            const int ng = n0 + wn * 64 + fn * 32 + ln;
            const int h = (ng >> 6) & 7, d = ng & 63;
            u16* base = (which == 0) ? Qb : ((which == 1) ? Kb : Vb);
#pragma unroll
            for (int r = 0; r < 16; ++r) {
                const int mg = m0 + wm * 64 + fm * 32 + (r & 3) + 8 * (r >> 2) + 4 * hi;
                if (mg < M1c) {
                    const int b = mg / NTc, t = mg - b * NTc;
                    base[((size_t)((b * Hc + h) * NTc + t)) * Dc + d] = (u16)f2bf1(acc[fm][fn][r]);
                }
            }
        }
}

// ---------------------------------------------------------------------------
// Out GEMM, split-bf16 3-pass, BK=32 double-buffered global_load_lds staging.
// ---------------------------------------------------------------------------
__global__ __launch_bounds__(256)
void gemm_out(const u16* __restrict__ Ahg, const u16* __restrict__ Alg,
              const u16* __restrict__ Bhg, const u16* __restrict__ Blg,
              float* __restrict__ Out)
{
    __shared__ __align__(16) u16 lds[2 * 12288];      // 2 x 24 KB
    char* L = (char*)lds;

    const int tid = threadIdx.x;
    const int wid = tid >> 6, lane = tid & 63, hi = lane >> 5, ln = lane & 31;
    const int wm = wid >> 1, wn = wid & 1;
    const int m0 = blockIdx.x * 128, n0 = blockIdx.y * 64;
    const int sr2 = tid >> 2;
    const int sc2 = tid & 3;

    f32x16 acc[2];
#pragma unroll
    for (int i = 0; i < 2; ++i)
#pragma unroll
        for (int r = 0; r < 16; ++r) acc[i][r] = 0.f;

#define OUT_STAGE(BUF, K0)                                                     \
    do {                                                                       \
        char* bb = L + (BUF) * 24576;                                          \
        _Pragma("unroll")                                                      \
        for (int i_ = 0; i_ < 2; ++i_) {                                       \
            const int row_ = i_ * 64 + sr2;                                    \
            const int gc_  = (sc2 ^ (row_ & 3)) * 8;                           \
            const size_t go_ = (size_t)(m0 + row_) * Cc + (K0) + gc_;          \
            gll16(Ahg + go_, bb + i_ * 4096 + tid * 16);                       \
            gll16(Alg + go_, bb + 8192 + i_ * 4096 + tid * 16);                \
        }                                                                      \
        {                                                                      \
            const int gc_  = (sc2 ^ (sr2 & 3)) * 8;                            \
            const size_t go_ = (size_t)(n0 + sr2) * Cc + (K0) + gc_;           \
            gll16(Bhg + go_, bb + 16384 + tid * 16);                           \
            gll16(Blg + go_, bb + 20480 + tid * 16);                           \
        }                                                                      \
    } while (0)

    OUT_STAGE(0, 0);
    __syncthreads();

    for (int k0 = 0; k0 < Cc; k0 += 32) {
        const int cur = (k0 >> 5) & 1;
        if (k0 + 32 < Cc) OUT_STAGE(cur ^ 1, k0 + 32);
        const char* bb = L + cur * 24576;
        const char* pAh = bb;
        const char* pAl = bb + 8192;
        const char* pBh = bb + 16384;
        const char* pBl = bb + 20480;
#pragma unroll
        for (int ks = 0; ks < 2; ++ks) {
            bf16x8 afh[2], afl[2], bfh, bfl;
#pragma unroll
            for (int f = 0; f < 2; ++f) {
                const int mr = wm * 64 + f * 32 + ln;
                const int moff = mr * 64 + (((ks * 2 + hi) ^ (mr & 3)) << 4);
                afh[f] = *(const bf16x8*)(pAh + moff);
                afl[f] = *(const bf16x8*)(pAl + moff);
            }
            {
                const int nr = wn * 32 + ln;
                const int noff = nr * 64 + (((ks * 2 + hi) ^ (nr & 3)) << 4);
                bfh = *(const bf16x8*)(pBh + noff);
                bfl = *(const bf16x8*)(pBl + noff);
            }
#pragma unroll
            for (int fm = 0; fm < 2; ++fm) {
                acc[fm] = MFMA32(afh[fm], bfh, acc[fm]);
                acc[fm] = MFMA32(afl[fm], bfh, acc[fm]);
                acc[fm] = MFMA32(afh[fm], bfl, acc[fm]);
            }
        }
        __syncthreads();
    }
#undef OUT_STAGE

#pragma unroll
    for (int fm = 0; fm < 2; ++fm) {
        const int ng = n0 + wn * 32 + ln;
#pragma unroll
        for (int r = 0; r < 16; ++r) {
            const int mg = m0 + wm * 64 + fm * 32 + (r & 3) + 8 * (r >> 2) + 4 * hi;
            Out[(size_t)mg * Cc + ng] = acc[fm][r];
        }
    }
}

// ---------------------------------------------------------------------------
// MFMA flash attention, split-K x3, 4 waves x 32 queries (128 q/block).
// FROZEN round-12 register structure. XCD-aware block swizzle (T1): grid
// 1728 = 8 x 216; s = (blk%8)*216 + blk/8 gives each XCD 216 consecutive
// semantic ids = exactly 4 whole (b,h) heads (54 ids each) -> per-XCD L2
// serves that head group's K/V instead of every XCD fetching all heads.
// ---------------------------------------------------------------------------
__global__ __launch_bounds__(256)
void attn_mfma(const u16* __restrict__ Qbf, const u16* __restrict__ Kbf,
               const u16* __restrict__ Vtg, const float* __restrict__ temp,
               float* __restrict__ Op, float* __restrict__ Rs)
{
    __shared__ __align__(16) u16 ldsKV[2][2][4096];   // [buf][K/V] 8 KB each
    char* L = (char*)ldsKV;

    const int tid  = threadIdx.x;
    const int wid  = tid >> 6;
    const int lane = tid & 63;
    const int hi   = lane >> 5;
    const int ln   = lane & 31;
    // XCD-aware bijective swizzle (nwg = 1728 = 8*216, exact)
    const int blk  = (blockIdx.x & 7) * (Bc * Hc * QT128 * NSPL / 8)
                   + (blockIdx.x >> 3);
    const int sp   = blk % NSPL;               // key-range split 0..2
    const int qb   = blk / NSPL;
    const int bh   = qb / QT128;
    const int qt   = qb - bh * QT128;
    const int b    = bh >> 3, h = bh & 7;
    const int qbase = qt * 128 + wid * 32;
    const float mlc = fabsf(temp[h]) * LOG2E;
    const int ktb = (sp == 0) ? 0 : (sp == 1 ? 13 : 26);
    const int kte = (sp == 0) ? 13 : (sp == 1 ? 26 : (KT64 + 1));

    const u16* Qrow = Qbf + ((size_t)bh * NTc + qbase + ln) * Dc;
    bf16x8 qf[4];
#pragma unroll
    for (int ks = 0; ks < 4; ++ks)
        qf[ks] = *(const bf16x8*)(Qrow + ks * 16 + hi * 8);

    U4 ones;
    ones.u[0] = ones.u[1] = ones.u[2] = ones.u[3] = 0x3F803F80u;  // bf16 1.0 x8

    f32x16 o0, o1, rsacc;
#pragma unroll
    for (int r = 0; r < 16; ++r) { o0[r] = 0.f; o1[r] = 0.f; rsacc[r] = 0.f; }

    const u16* Kbh = Kbf + (size_t)bh * NTc * Dc;
    const u16* Vbh = Vtg + (size_t)bh * Dc * NTc;

    const int sc  = tid & 7;
    const int sr0 = tid >> 3;

#define ATTN_STAGE(BUF, KB)                                                    \
    do {                                                                       \
        char* Kd = L + (BUF) * 16384;                                          \
        char* Vd = Kd + 8192;                                                  \
        _Pragma("unroll")                                                      \
        for (int half_ = 0; half_ < 2; ++half_) {                              \
            const int r_ = sr0 + half_ * 32;                                   \
            const int gc_ = (sc ^ (r_ & 7)) * 8;                               \
            int rK = (KB) + r_;   if (rK > NTc - 1) rK = NTc - 1;              \
            int cV = (KB) + gc_;  if (cV > NTc - 8) cV = NTc - 8;              \
            gll16(Kbh + (size_t)rK * Dc + gc_, Kd + half_ * 4096 + tid * 16);  \
            gll16(Vbh + (size_t)r_ * NTc + cV, Vd + half_ * 4096 + tid * 16);  \
        }                                                                      \
    } while (0)

    ATTN_STAGE(0, ktb * 64);
    __syncthreads();

    for (int kt = ktb; kt < kte; ++kt) {
        const int  cur  = (kt - ktb) & 1;      // relative parity: any ktb
        const bool tail = (kt == KT64);
        if (kt + 1 < kte) ATTN_STAGE(cur ^ 1, (kt + 1) * 64);
        const char* Kc = L + cur * 16384;
        const char* Vc = Kc + 8192;

        const int nsub = tail ? 1 : 2;
        for (int kt2 = 0; kt2 < nsub; ++kt2) {
            f32x16 s;
#pragma unroll
            for (int r = 0; r < 16; ++r) s[r] = 0.f;
            const int krow = kt2 * 32 + ln;
            const char* kbc = Kc + (krow << 7);
            const int   ksz = (krow & 7) << 4;
            __builtin_amdgcn_s_setprio(1);
#pragma unroll
            for (int ks = 0; ks < 4; ++ks) {
                const bf16x8 kf = *(const bf16x8*)(kbc + (((ks << 5) + (hi << 4)) ^ ksz));
                s = MFMA32(kf, qf[ks], s);
            }
            __builtin_amdgcn_s_setprio(0);

            float p[16];
#pragma unroll
            for (int r = 0; r < 16; ++r)
                p[r] = __builtin_amdgcn_exp2f(fmaf(s[r], LOG2E, -mlc));
            if (tail) {
#pragma unroll
                for (int r = 4; r < 16; ++r) p[r] = 0.f;   // keys >= 8 invalid
            }

            u32 a0 = pkb(p[0],  p[1]),  a1 = pkb(p[2],  p[3]);
            u32 b0 = pkb(p[4],  p[5]),  b1 = pkb(p[6],  p[7]);
            u32 c0 = pkb(p[8],  p[9]),  c1 = pkb(p[10], p[11]);
            u32 d0 = pkb(p[12], p[13]), d1 = pkb(p[14], p[15]);
            asm("v_permlane32_swap_b32 %0, %1" : "+v"(a0), "+v"(b0));
            asm("v_permlane32_swap_b32 %0, %1" : "+v"(a1), "+v"(b1));
            asm("v_permlane32_swap_b32 %0, %1" : "+v"(c0), "+v"(d0));
            asm("v_permlane32_swap_b32 %0, %1" : "+v"(c1), "+v"(d1));
            U4 f0, f1;
            f0.u[0] = a0; f0.u[1] = a1; f0.u[2] = b0; f0.u[3] = b1;
            f1.u[0] = c0; f1.u[1] = c1; f1.u[2] = d0; f1.u[3] = d1;

            const char* v0c = Vc + (ln << 7);
            const char* v1c = Vc + ((32 + ln) << 7);
            const int   vsz0 = (ln & 7) << 4;
            const int   cof0 = ((kt2 << 6) + (hi << 4)) ^ vsz0;
            const int   cof1 = ((kt2 << 6) + 32 + (hi << 4)) ^ vsz0;
            __builtin_amdgcn_s_setprio(1);
            rsacc = MFMA32(ones.f, f0.f, rsacc);
            o0 = MFMA32(*(const bf16x8*)(v0c + cof0), f0.f, o0);
            o1 = MFMA32(*(const bf16x8*)(v1c + cof0), f0.f, o1);
            if (!tail) {
                rsacc = MFMA32(ones.f, f1.f, rsacc);
                o0 = MFMA32(*(const bf16x8*)(v0c + cof1), f1.f, o0);
                o1 = MFMA32(*(const bf16x8*)(v1c + cof1), f1.f, o1);
            }
            __builtin_amdgcn_s_setprio(0);
        }
        __syncthreads();
    }
#undef ATTN_STAGE

    if (hi == 0)
        Rs[((size_t)sp * 32 + bh) * Nc + qbase + ln] = rsacc[0];

    float* Po = Op + (size_t)sp * M2c * Cc
                   + ((size_t)b * Nc + qbase + ln) * Cc + h * Dc;
#pragma unroll
    for (int g = 0; g < 4; ++g) {
        *(float4*)(Po + 8 * g + 4 * hi) =
            make_float4(o0[4*g], o0[4*g+1], o0[4*g+2], o0[4*g+3]);
        *(float4*)(Po + 32 + 8 * g + 4 * hi) =
            make_float4(o1[4*g], o1[4*g+1], o1[4*g+2], o1[4*g+3]);
    }
}

// ---------------------------------------------------------------------------
// Merge split-K x3 partials: O = (Oa+Ob+Oc)/(rsa+rsb+rsc); hi/lo bf16 out.
// ---------------------------------------------------------------------------
__global__ __launch_bounds__(256)
void merge_o(const float* __restrict__ Op, const float* __restrict__ Rs,
             u16* __restrict__ Oh, u16* __restrict__ Ol)
{
    const int id = blockIdx.x * 256 + threadIdx.x;    // 4 floats per thread
    const size_t base = (size_t)id * 4;
    const int row = id >> 7;
    const int c   = (int)(base & 511);
    const int b   = row / Nc, qi = row - b * Nc;
    const int bh  = b * Hc + (c >> 6);
    const float rs = Rs[(size_t)bh * Nc + qi]
                   + Rs[(size_t)(32 + bh) * Nc + qi]
                   + Rs[(size_t)(64 + bh) * Nc + qi];
    const float inv = 1.0f / rs;
    const float4 va = *(const float4*)(Op + base);
    const float4 vb = *(const float4*)(Op + (size_t)M2c * Cc + base);
    const float4 vc = *(const float4*)(Op + 2 * (size_t)M2c * Cc + base);
    const float x0 = (va.x + vb.x + vc.x) * inv, x1 = (va.y + vb.y + vc.y) * inv;
    const float x2 = (va.z + vb.z + vc.z) * inv, x3 = (va.w + vb.w + vc.w) * inv;
    const u32 h0 = f2bf1(x0), h1 = f2bf1(x1), h2 = f2bf1(x2), h3 = f2bf1(x3);
    uint2 hv, lv;
    hv.x = h0 | (h1 << 16);
    hv.y = h2 | (h3 << 16);
    lv.x = pk2(x0 - __uint_as_float(h0 << 16), x1 - __uint_as_float(h1 << 16));
    lv.y = pk2(x2 - __uint_as_float(h2 << 16), x3 - __uint_as_float(h3 << 16));
    *(uint2*)(Oh + base) = hv;
    *(uint2*)(Ol + base) = lv;
}

// ---------------------------------------------------------------------------
extern "C" void kernel_launch(void* const* d_in, const int* in_sizes, int n_in,
                              void* d_out, int out_size, void* d_ws, size_t ws_size,
                              hipStream_t stream)
{
    const float* X    = (const float*)d_in[0];
    const float* S    = (const float*)d_in[1];
    const float* Wqkv = (const float*)d_in[2];
    const float* Wout = (const float*)d_in[3];
    const float* temp = (const float*)d_in[4];
    float* out = (float*)d_out;

    u16* ws16 = (u16*)d_ws;
    const size_t R  = (size_t)M1c * Cc;     // 4,734,976 u16
    const size_t RO = (size_t)M2c * Cc;     // 4,718,592

    // Op region: 3 x RO f32 = 6*RO u16, aliasing Abf, Vbf, WqT (all dead
    // before attn writes Op).
    float* Op  = (float*)ws16;
    u16*  Abf  = ws16;                      // [0, R)
    u16*  Vbf  = ws16 + R;                  // [R, 2R)
    u16*  WqT  = ws16 + 2 * R;              // [2R, 2R+N1c*Cc)  << 6*RO
    u16*  WoTh = ws16 + 6 * RO;
    u16*  WoTl = WoTh + (size_t)Cc * Cc;
    u16*  Qbf  = WoTl + (size_t)Cc * Cc;
    u16*  Kbf  = Qbf + R;
    u16*  Vt   = Kbf + R;
    float* Rs  = (float*)(Vt + R);          // NSPL*32*Nc floats
    u16*  Oh   = Qbf;                       // alias: Qbf dead after attn
    u16*  Ol   = Kbf;                       // alias: Kbf dead after attn

    // 1) input concat + bf16 cast
    cvt_concat<<<M1c * (Cc / 8) / 256, 256, 0, stream>>>(X, S, Abf);
    // 2) weight transpose-casts
    cvt_w<false><<<dim3(N1c / 64, Cc / 64), 256, 0, stream>>>(Wqkv, N1c, WqT, nullptr);
    cvt_w<true ><<<dim3(Cc  / 64, Cc / 64), 256, 0, stream>>>(Wout, Cc,  WoTh, WoTl);
    // 3) QKV GEMM with fused q/k normalization
    gemm_qkv<<<dim3((M1c + 127) / 128, N1c / 128), 256, 0, stream>>>(Abf, WqT, temp, Qbf, Kbf, Vbf);
    // 4) V transpose -> (B,H,D,Nt)
    transpose_v<<<dim3(Bc * Hc, (NTc + 63) / 64), 256, 0, stream>>>(Vbf, Vt);
    // 5) attention split-K x3 (XCD-swizzled) -> partials
    attn_mfma<<<Bc * Hc * QT128 * NSPL, 256, 0, stream>>>(Qbf, Kbf, Vt, temp, Op, Rs);
    // 6) merge partials -> Oattn hi/lo bf16 (aliases dead Qbf/Kbf)
    merge_o<<<(int)(RO / 4 / 256), 256, 0, stream>>>(Op, Rs, Oh, Ol);
    // 7) out GEMM (split-bf16 3-pass, BK=32 double-buffered) -> f32 out
    gemm_out<<<dim3(M2c / 128, Cc / 64), 256, 0, stream>>>(Oh, Ol, WoTh, WoTl, out);
}

// Round 18
// 157.981 us; speedup vs baseline: 1.1616x; 1.0798x over previous
//
#include <hip/hip_runtime.h>
#include <math.h>

typedef unsigned short u16;
typedef unsigned int   u32;
typedef __attribute__((ext_vector_type(8)))  __bf16 bf16x8;
typedef __attribute__((ext_vector_type(16))) float  f32x16;

constexpr int Bc  = 4;
constexpr int Nc  = 2304;
constexpr int KSc = 8;
constexpr int Cc  = 512;
constexpr int Hc  = 8;
constexpr int Dc  = 64;
constexpr int NTc = Nc + KSc;          // 2312
constexpr int M1c = Bc * NTc;          // 9248
constexpr int N1c = 3 * Cc;            // 1536
constexpr int M2c = Bc * Nc;           // 9216
constexpr int QT128 = Nc / 128;        // 18 query tiles of 128
constexpr int KT64  = NTc / 64;        // 36 full tiles (+8 tail)
constexpr int NSPL  = 3;               // split-K factor
constexpr float LOG2E = 1.4426950408889634f;

__device__ __forceinline__ u32 f2bf1(float f) {
    u32 u = __float_as_uint(f);
    return (u + 0x7fffu + ((u >> 16) & 1u)) >> 16;   // RNE bf16
}
__device__ __forceinline__ u32 pk2(float lo, float hi) {
    u32 ul = __float_as_uint(lo);
    u32 uh = __float_as_uint(hi);
    ul = (ul + 0x7fffu + ((ul >> 16) & 1u)) >> 16;
    uh = (uh + 0x7fffu + ((uh >> 16) & 1u)) & 0xffff0000u;
    return ul | uh;
}
__device__ __forceinline__ float bf2f(u16 x) {
    return __uint_as_float(((u32)x) << 16);
}
__device__ __forceinline__ u32 pkb(float lo, float hi) {
    union { u32 u; __bf16 h[2]; } t;
    t.h[0] = (__bf16)lo; t.h[1] = (__bf16)hi;
    return t.u;
}
// async global->LDS, 16B per lane; LDS dest = wave base + lane*16 (linear)
__device__ __forceinline__ void gll16(const u16* g, char* l) {
    __builtin_amdgcn_global_load_lds(
        (const __attribute__((address_space(1))) unsigned int*)g,
        (__attribute__((address_space(3))) unsigned int*)l, 16, 0, 0);
}

#define MFMA32(A, B, C) __builtin_amdgcn_mfma_f32_32x32x16_bf16(A, B, C, 0, 0, 0)

union U4 { u32 u[4]; bf16x8 f; };

// ---------------------------------------------------------------------------
// concat(X,S) -> bf16 A [M1][512]
// ---------------------------------------------------------------------------
__global__ __launch_bounds__(256)
void cvt_concat(const float* __restrict__ X, const float* __restrict__ S,
                u16* __restrict__ A)
{
    const int id  = blockIdx.x * 256 + threadIdx.x;
    const int row = id >> 6;
    const int ch  = (id & 63) * 8;
    const int b = row / NTc, t = row - b * NTc;
    const float* src = (t < Nc) ? X + ((size_t)(b * Nc + t)) * Cc + ch
                                : S + ((size_t)(b * KSc + (t - Nc))) * Cc + ch;
    const float4 v0 = ((const float4*)src)[0];
    const float4 v1 = ((const float4*)src)[1];
    u32 w[4];
    w[0] = pk2(v0.x, v0.y); w[1] = pk2(v0.z, v0.w);
    w[2] = pk2(v1.x, v1.y); w[3] = pk2(v1.z, v1.w);
    *(uint4*)(A + (size_t)row * Cc + ch) = *(const uint4*)w;
}

// ---------------------------------------------------------------------------
// Transpose-cast weights: W [512][Nn] f32 -> WT [Nn][512] bf16
// ---------------------------------------------------------------------------
__global__ __launch_bounds__(256)
void cvt_w(const float* __restrict__ W, int Nn, u16* __restrict__ WT)
{
    __shared__ float Ws[64][68];
    const int n0 = blockIdx.x * 64, k0 = blockIdx.y * 64;
#pragma unroll
    for (int i = 0; i < 4; ++i) {
        const int c = i * 256 + threadIdx.x;
        const int kr = c >> 4, nc = (c & 15) * 4;
        const float4 v = *(const float4*)(W + (size_t)(k0 + kr) * Nn + n0 + nc);
        Ws[kr][nc] = v.x; Ws[kr][nc+1] = v.y; Ws[kr][nc+2] = v.z; Ws[kr][nc+3] = v.w;
    }
    __syncthreads();
#pragma unroll
    for (int i = 0; i < 2; ++i) {
        const int c = i * 256 + threadIdx.x;
        const int n = c >> 3, kc = (c & 7) * 8;
        u32 wh[4];
#pragma unroll
        for (int j = 0; j < 4; ++j)
            wh[j] = pk2(Ws[kc + 2*j][n], Ws[kc + 2*j + 1][n]);
        *(uint4*)(WT + (size_t)(n0 + n) * Cc + k0 + kc) = *(const uint4*)wh;
    }
}

// ---------------------------------------------------------------------------
// V (B,H,Nt,D) bf16 -> Vt (B,H,D,Nt) bf16
// ---------------------------------------------------------------------------
__global__ __launch_bounds__(256)
void transpose_v(const u16* __restrict__ Vbf, u16* __restrict__ Vt)
{
    __shared__ u16 Vs[64][80];
    const int bh = blockIdx.x;
    const int t0 = blockIdx.y * 64;
    const u16* src = Vbf + (size_t)bh * NTc * Dc;
#pragma unroll
    for (int i = 0; i < 2; ++i) {
        const int c = i * 256 + threadIdx.x;
        const int tr = c >> 3, dc = (c & 7) * 8;
        int tg = t0 + tr; if (tg > NTc - 1) tg = NTc - 1;
        const uint4 v = *(const uint4*)(src + (size_t)tg * Dc + dc);
        *(uint4*)&Vs[tr][dc] = v;
    }
    __syncthreads();
#pragma unroll
    for (int i = 0; i < 2; ++i) {
        const int c = i * 256 + threadIdx.x;
        const int d = c >> 3, tch = (c & 7) * 8;
        if (t0 + tch + 7 <= NTc - 1) {
            u16 tmp[8];
#pragma unroll
            for (int j = 0; j < 8; ++j) tmp[j] = Vs[tch + j][d];
            *(uint4*)(Vt + ((size_t)bh * Dc + d) * NTc + t0 + tch) = *(const uint4*)tmp;
        }
    }
}

// ---------------------------------------------------------------------------
// QKV GEMM, bf16 MFMA, global_load_lds double-buffered staging.
// Fused q/k L2-norm epilogue.
// ---------------------------------------------------------------------------
__global__ __launch_bounds__(256)
void gemm_qkv(const u16* __restrict__ A, const u16* __restrict__ Bw,
              const float* __restrict__ temp,
              u16* __restrict__ Qb, u16* __restrict__ Kb, u16* __restrict__ Vb)
{
    __shared__ __align__(16) u16 lds[2 * 2 * 8192];   // [buf][A/B] 16 KB each
    char* L = (char*)lds;

    const int tid = threadIdx.x;
    const int wid = tid >> 6, lane = tid & 63, hi = lane >> 5, ln = lane & 31;
    const int wm = wid >> 1, wn = wid & 1;
    const int m0 = blockIdx.x * 128, n0 = blockIdx.y * 128;

    const int sr = tid >> 3;
    const int sc = tid & 7;

    f32x16 acc[2][2];
#pragma unroll
    for (int i = 0; i < 2; ++i)
#pragma unroll
        for (int j = 0; j < 2; ++j)
#pragma unroll
            for (int r = 0; r < 16; ++r) acc[i][j][r] = 0.f;

#define QKV_STAGE(BUF, K0)                                                     \
    do {                                                                       \
        char* dA = L + (BUF) * 32768;                                          \
        char* dB = dA + 16384;                                                 \
        _Pragma("unroll")                                                      \
        for (int i_ = 0; i_ < 4; ++i_) {                                       \
            const int row_ = i_ * 32 + sr;                                     \
            const int gc_  = (sc ^ (row_ & 7)) * 8;                            \
            int mg_ = m0 + row_; if (mg_ > M1c - 1) mg_ = M1c - 1;             \
            gll16(A  + (size_t)mg_ * Cc + (K0) + gc_,                          \
                  dA + i_ * 4096 + tid * 16);                                  \
            gll16(Bw + (size_t)(n0 + row_) * Cc + (K0) + gc_,                  \
                  dB + i_ * 4096 + tid * 16);                                  \
        }                                                                      \
    } while (0)

    QKV_STAGE(0, 0);
    __syncthreads();

    for (int k0 = 0; k0 < Cc; k0 += 64) {
        const int cur = (k0 >> 6) & 1;
        if (k0 + 64 < Cc) QKV_STAGE(cur ^ 1, k0 + 64);
        const char* ldsA = L + cur * 32768;
        const char* ldsB = ldsA + 16384;
#pragma unroll
        for (int ks = 0; ks < 4; ++ks) {
            bf16x8 af[2], bfr[2];
#pragma unroll
            for (int f = 0; f < 2; ++f) {
                const int mr = wm * 64 + f * 32 + ln;
                af[f]  = *(const bf16x8*)(ldsA + mr * 128 + (((ks * 2 + hi) ^ (mr & 7)) << 4));
                const int nr = wn * 64 + f * 32 + ln;
                bfr[f] = *(const bf16x8*)(ldsB + nr * 128 + (((ks * 2 + hi) ^ (nr & 7)) << 4));
            }
#pragma unroll
            for (int fm = 0; fm < 2; ++fm)
#pragma unroll
                for (int fn = 0; fn < 2; ++fn)
                    acc[fm][fn] = MFMA32(af[fm], bfr[fn], acc[fm][fn]);
        }
        __syncthreads();
    }
#undef QKV_STAGE

    const int which = n0 >> 9;
    const int hh = ((n0 + wn * 64) >> 6) & 7;

    if (which < 2) {
        const float tsc = (which == 0) ? temp[hh] : 1.0f;
#pragma unroll
        for (int fm = 0; fm < 2; ++fm)
#pragma unroll
            for (int r = 0; r < 16; ++r) {
                float ss = fmaf(acc[fm][0][r], acc[fm][0][r],
                                acc[fm][1][r] * acc[fm][1][r]);
                ss += __shfl_xor(ss, 1);
                ss += __shfl_xor(ss, 2);
                ss += __shfl_xor(ss, 4);
                ss += __shfl_xor(ss, 8);
                ss += __shfl_xor(ss, 16);
                const float scl = tsc / fmaxf(sqrtf(ss), 1e-12f);
                acc[fm][0][r] *= scl;
                acc[fm][1][r] *= scl;
            }
    }

#pragma unroll
    for (int fm = 0; fm < 2; ++fm)
#pragma unroll
        for (int fn = 0; fn < 2; ++fn) {
            const int ng = n0 + wn * 64 + fn * 32 + ln;
            const int h = (ng >> 6) & 7, d = ng & 63;
            u16* base = (which == 0) ? Qb : ((which == 1) ? Kb : Vb);
#pragma unroll
            for (int r = 0; r < 16; ++r) {
                const int mg = m0 + wm * 64 + fm * 32 + (r & 3) + 8 * (r >> 2) + 4 * hi;
                if (mg < M1c) {
                    const int b = mg / NTc, t = mg - b * NTc;
                    base[((size_t)((b * Hc + h) * NTc + t)) * Dc + d] = (u16)f2bf1(acc[fm][fn][r]);
                }
            }
        }
}

// ---------------------------------------------------------------------------
// Out GEMM, SINGLE-PASS bf16 (lo-terms dropped; error budget re-derived:
// O rms ~0.02 -> added worst-case error ~5e-4, total ~1e-3 < 1.855e-3).
// BK=32 double-buffered global_load_lds staging. Per-buffer: Ah 8KB + Bh 4KB.
// ---------------------------------------------------------------------------
__global__ __launch_bounds__(256)
void gemm_out(const u16* __restrict__ Ahg, const u16* __restrict__ Bhg,
              float* __restrict__ Out)
{
    __shared__ __align__(16) u16 lds[2 * 6144];       // 2 x 12 KB
    char* L = (char*)lds;

    const int tid = threadIdx.x;
    const int wid = tid >> 6, lane = tid & 63, hi = lane >> 5, ln = lane & 31;
    const int wm = wid >> 1, wn = wid & 1;
    const int m0 = blockIdx.x * 128, n0 = blockIdx.y * 64;
    const int sr2 = tid >> 2;
    const int sc2 = tid & 3;

    f32x16 acc[2];
#pragma unroll
    for (int i = 0; i < 2; ++i)
#pragma unroll
        for (int r = 0; r < 16; ++r) acc[i][r] = 0.f;

    // per-buffer layout: Ah [0,8192) Bh [8192,12288)
#define OUT_STAGE(BUF, K0)                                                     \
    do {                                                                       \
        char* bb = L + (BUF) * 12288;                                          \
        _Pragma("unroll")                                                      \
        for (int i_ = 0; i_ < 2; ++i_) {                                       \
            const int row_ = i_ * 64 + sr2;                                    \
            const int gc_  = (sc2 ^ (row_ & 3)) * 8;                           \
            const size_t go_ = (size_t)(m0 + row_) * Cc + (K0) + gc_;          \
            gll16(Ahg + go_, bb + i_ * 4096 + tid * 16);                       \
        }                                                                      \
        {                                                                      \
            const int gc_  = (sc2 ^ (sr2 & 3)) * 8;                            \
            const size_t go_ = (size_t)(n0 + sr2) * Cc + (K0) + gc_;           \
            gll16(Bhg + go_, bb + 8192 + tid * 16);                            \
        }                                                                      \
    } while (0)

    OUT_STAGE(0, 0);
    __syncthreads();

    for (int k0 = 0; k0 < Cc; k0 += 32) {
        const int cur = (k0 >> 5) & 1;
        if (k0 + 32 < Cc) OUT_STAGE(cur ^ 1, k0 + 32);
        const char* bb = L + cur * 12288;
        const char* pAh = bb;
        const char* pBh = bb + 8192;
#pragma unroll
        for (int ks = 0; ks < 2; ++ks) {
            bf16x8 afh[2], bfh;
#pragma unroll
            for (int f = 0; f < 2; ++f) {
                const int mr = wm * 64 + f * 32 + ln;
                const int moff = mr * 64 + (((ks * 2 + hi) ^ (mr & 3)) << 4);
                afh[f] = *(const bf16x8*)(pAh + moff);
            }
            {
                const int nr = wn * 32 + ln;
                const int noff = nr * 64 + (((ks * 2 + hi) ^ (nr & 3)) << 4);
                bfh = *(const bf16x8*)(pBh + noff);
            }
#pragma unroll
            for (int fm = 0; fm < 2; ++fm)
                acc[fm] = MFMA32(afh[fm], bfh, acc[fm]);
        }
        __syncthreads();
    }
#undef OUT_STAGE

#pragma unroll
    for (int fm = 0; fm < 2; ++fm) {
        const int ng = n0 + wn * 32 + ln;
#pragma unroll
        for (int r = 0; r < 16; ++r) {
            const int mg = m0 + wm * 64 + fm * 32 + (r & 3) + 8 * (r >> 2) + 4 * hi;
            Out[(size_t)mg * Cc + ng] = acc[fm][r];
        }
    }
}

// ---------------------------------------------------------------------------
// MFMA flash attention, split-K x3, 4 waves x 32 queries (128 q/block).
// FROZEN round-12 register structure + XCD-aware block swizzle (T1).
// ---------------------------------------------------------------------------
__global__ __launch_bounds__(256)
void attn_mfma(const u16* __restrict__ Qbf, const u16* __restrict__ Kbf,
               const u16* __restrict__ Vtg, const float* __restrict__ temp,
               float* __restrict__ Op, float* __restrict__ Rs)
{
    __shared__ __align__(16) u16 ldsKV[2][2][4096];   // [buf][K/V] 8 KB each
    char* L = (char*)ldsKV;

    const int tid  = threadIdx.x;
    const int wid  = tid >> 6;
    const int lane = tid & 63;
    const int hi   = lane >> 5;
    const int ln   = lane & 31;
    // XCD-aware bijective swizzle (nwg = 1728 = 8*216, exact)
    const int blk  = (blockIdx.x & 7) * (Bc * Hc * QT128 * NSPL / 8)
                   + (blockIdx.x >> 3);
    const int sp   = blk % NSPL;               // key-range split 0..2
    const int qb   = blk / NSPL;
    const int bh   = qb / QT128;
    const int qt   = qb - bh * QT128;
    const int b    = bh >> 3, h = bh & 7;
    const int qbase = qt * 128 + wid * 32;
    const float mlc = fabsf(temp[h]) * LOG2E;
    const int ktb = (sp == 0) ? 0 : (sp == 1 ? 13 : 26);
    const int kte = (sp == 0) ? 13 : (sp == 1 ? 26 : (KT64 + 1));

    const u16* Qrow = Qbf + ((size_t)bh * NTc + qbase + ln) * Dc;
    bf16x8 qf[4];
#pragma unroll
    for (int ks = 0; ks < 4; ++ks)
        qf[ks] = *(const bf16x8*)(Qrow + ks * 16 + hi * 8);

    U4 ones;
    ones.u[0] = ones.u[1] = ones.u[2] = ones.u[3] = 0x3F803F80u;  // bf16 1.0 x8

    f32x16 o0, o1, rsacc;
#pragma unroll
    for (int r = 0; r < 16; ++r) { o0[r] = 0.f; o1[r] = 0.f; rsacc[r] = 0.f; }

    const u16* Kbh = Kbf + (size_t)bh * NTc * Dc;
    const u16* Vbh = Vtg + (size_t)bh * Dc * NTc;

    const int sc  = tid & 7;
    const int sr0 = tid >> 3;

#define ATTN_STAGE(BUF, KB)                                                    \
    do {                                                                       \
        char* Kd = L + (BUF) * 16384;                                          \
        char* Vd = Kd + 8192;                                                  \
        _Pragma("unroll")                                                      \
        for (int half_ = 0; half_ < 2; ++half_) {                              \
            const int r_ = sr0 + half_ * 32;                                   \
            const int gc_ = (sc ^ (r_ & 7)) * 8;                               \
            int rK = (KB) + r_;   if (rK > NTc - 1) rK = NTc - 1;              \
            int cV = (KB) + gc_;  if (cV > NTc - 8) cV = NTc - 8;              \
            gll16(Kbh + (size_t)rK * Dc + gc_, Kd + half_ * 4096 + tid * 16);  \
            gll16(Vbh + (size_t)r_ * NTc + cV, Vd + half_ * 4096 + tid * 16);  \
        }                                                                      \
    } while (0)

    ATTN_STAGE(0, ktb * 64);
    __syncthreads();

    for (int kt = ktb; kt < kte; ++kt) {
        const int  cur  = (kt - ktb) & 1;      // relative parity: any ktb
        const bool tail = (kt == KT64);
        if (kt + 1 < kte) ATTN_STAGE(cur ^ 1, (kt + 1) * 64);
        const char* Kc = L + cur * 16384;
        const char* Vc = Kc + 8192;

        const int nsub = tail ? 1 : 2;
        for (int kt2 = 0; kt2 < nsub; ++kt2) {
            f32x16 s;
#pragma unroll
            for (int r = 0; r < 16; ++r) s[r] = 0.f;
            const int krow = kt2 * 32 + ln;
            const char* kbc = Kc + (krow << 7);
            const int   ksz = (krow & 7) << 4;
            __builtin_amdgcn_s_setprio(1);
#pragma unroll
            for (int ks = 0; ks < 4; ++ks) {
                const bf16x8 kf = *(const bf16x8*)(kbc + (((ks << 5) + (hi << 4)) ^ ksz));
                s = MFMA32(kf, qf[ks], s);
            }
            __builtin_amdgcn_s_setprio(0);

            float p[16];
#pragma unroll
            for (int r = 0; r < 16; ++r)
                p[r] = __builtin_amdgcn_exp2f(fmaf(s[r], LOG2E, -mlc));
            if (tail) {
#pragma unroll
                for (int r = 4; r < 16; ++r) p[r] = 0.f;   // keys >= 8 invalid
            }

            u32 a0 = pkb(p[0],  p[1]),  a1 = pkb(p[2],  p[3]);
            u32 b0 = pkb(p[4],  p[5]),  b1 = pkb(p[6],  p[7]);
            u32 c0 = pkb(p[8],  p[9]),  c1 = pkb(p[10], p[11]);
            u32 d0 = pkb(p[12], p[13]), d1 = pkb(p[14], p[15]);
            asm("v_permlane32_swap_b32 %0, %1" : "+v"(a0), "+v"(b0));
            asm("v_permlane32_swap_b32 %0, %1" : "+v"(a1), "+v"(b1));
            asm("v_permlane32_swap_b32 %0, %1" : "+v"(c0), "+v"(d0));
            asm("v_permlane32_swap_b32 %0, %1" : "+v"(c1), "+v"(d1));
            U4 f0, f1;
            f0.u[0] = a0; f0.u[1] = a1; f0.u[2] = b0; f0.u[3] = b1;
            f1.u[0] = c0; f1.u[1] = c1; f1.u[2] = d0; f1.u[3] = d1;

            const char* v0c = Vc + (ln << 7);
            const char* v1c = Vc + ((32 + ln) << 7);
            const int   vsz0 = (ln & 7) << 4;
            const int   cof0 = ((kt2 << 6) + (hi << 4)) ^ vsz0;
            const int   cof1 = ((kt2 << 6) + 32 + (hi << 4)) ^ vsz0;
            __builtin_amdgcn_s_setprio(1);
            rsacc = MFMA32(ones.f, f0.f, rsacc);
            o0 = MFMA32(*(const bf16x8*)(v0c + cof0), f0.f, o0);
            o1 = MFMA32(*(const bf16x8*)(v1c + cof0), f0.f, o1);
            if (!tail) {
                rsacc = MFMA32(ones.f, f1.f, rsacc);
                o0 = MFMA32(*(const bf16x8*)(v0c + cof1), f1.f, o0);
                o1 = MFMA32(*(const bf16x8*)(v1c + cof1), f1.f, o1);
            }
            __builtin_amdgcn_s_setprio(0);
        }
        __syncthreads();
    }
#undef ATTN_STAGE

    if (hi == 0)
        Rs[((size_t)sp * 32 + bh) * Nc + qbase + ln] = rsacc[0];

    float* Po = Op + (size_t)sp * M2c * Cc
                   + ((size_t)b * Nc + qbase + ln) * Cc + h * Dc;
#pragma unroll
    for (int g = 0; g < 4; ++g) {
        *(float4*)(Po + 8 * g + 4 * hi) =
            make_float4(o0[4*g], o0[4*g+1], o0[4*g+2], o0[4*g+3]);
        *(float4*)(Po + 32 + 8 * g + 4 * hi) =
            make_float4(o1[4*g], o1[4*g+1], o1[4*g+2], o1[4*g+3]);
    }
}

// ---------------------------------------------------------------------------
// Merge split-K x3 partials: O = (Oa+Ob+Oc)/(rsa+rsb+rsc); bf16 (hi only).
// ---------------------------------------------------------------------------
__global__ __launch_bounds__(256)
void merge_o(const float* __restrict__ Op, const float* __restrict__ Rs,
             u16* __restrict__ Oh)
{
    const int id = blockIdx.x * 256 + threadIdx.x;    // 4 floats per thread
    const size_t base = (size_t)id * 4;
    const int row = id >> 7;
    const int c   = (int)(base & 511);
    const int b   = row / Nc, qi = row - b * Nc;
    const int bh  = b * Hc + (c >> 6);
    const float rs = Rs[(size_t)bh * Nc + qi]
                   + Rs[(size_t)(32 + bh) * Nc + qi]
                   + Rs[(size_t)(64 + bh) * Nc + qi];
    const float inv = 1.0f / rs;
    const float4 va = *(const float4*)(Op + base);
    const float4 vb = *(const float4*)(Op + (size_t)M2c * Cc + base);
    const float4 vc = *(const float4*)(Op + 2 * (size_t)M2c * Cc + base);
    uint2 hv;
    hv.x = pk2((va.x + vb.x + vc.x) * inv, (va.y + vb.y + vc.y) * inv);
    hv.y = pk2((va.z + vb.z + vc.z) * inv, (va.w + vb.w + vc.w) * inv);
    *(uint2*)(Oh + base) = hv;
}

// ---------------------------------------------------------------------------
extern "C" void kernel_launch(void* const* d_in, const int* in_sizes, int n_in,
                              void* d_out, int out_size, void* d_ws, size_t ws_size,
                              hipStream_t stream)
{
    const float* X    = (const float*)d_in[0];
    const float* S    = (const float*)d_in[1];
    const float* Wqkv = (const float*)d_in[2];
    const float* Wout = (const float*)d_in[3];
    const float* temp = (const float*)d_in[4];
    float* out = (float*)d_out;

    u16* ws16 = (u16*)d_ws;
    const size_t R  = (size_t)M1c * Cc;     // 4,734,976 u16
    const size_t RO = (size_t)M2c * Cc;     // 4,718,592

    // Op region: 3 x RO f32 = 6*RO u16, aliasing Abf, Vbf, WqT (all dead
    // before attn writes Op).
    float* Op  = (float*)ws16;
    u16*  Abf  = ws16;                      // [0, R)
    u16*  Vbf  = ws16 + R;                  // [R, 2R)
    u16*  WqT  = ws16 + 2 * R;              // [2R, 2R+N1c*Cc)  << 6*RO
    u16*  WoT  = ws16 + 6 * RO;
    u16*  Qbf  = WoT + (size_t)Cc * Cc;
    u16*  Kbf  = Qbf + R;
    u16*  Vt   = Kbf + R;
    float* Rs  = (float*)(Vt + R);          // NSPL*32*Nc floats
    u16*  Oh   = Qbf;                       // alias: Qbf dead after attn

    // 1) input concat + bf16 cast
    cvt_concat<<<M1c * (Cc / 8) / 256, 256, 0, stream>>>(X, S, Abf);
    // 2) weight transpose-casts (both plain bf16)
    cvt_w<<<dim3(N1c / 64, Cc / 64), 256, 0, stream>>>(Wqkv, N1c, WqT);
    cvt_w<<<dim3(Cc  / 64, Cc / 64), 256, 0, stream>>>(Wout, Cc,  WoT);
    // 3) QKV GEMM with fused q/k normalization
    gemm_qkv<<<dim3((M1c + 127) / 128, N1c / 128), 256, 0, stream>>>(Abf, WqT, temp, Qbf, Kbf, Vbf);
    // 4) V transpose -> (B,H,D,Nt)
    transpose_v<<<dim3(Bc * Hc, (NTc + 63) / 64), 256, 0, stream>>>(Vbf, Vt);
    // 5) attention split-K x3 (XCD-swizzled) -> partials
    attn_mfma<<<Bc * Hc * QT128 * NSPL, 256, 0, stream>>>(Qbf, Kbf, Vt, temp, Op, Rs);
    // 6) merge partials -> Oattn bf16 (aliases dead Qbf)
    merge_o<<<(int)(RO / 4 / 256), 256, 0, stream>>>(Op, Rs, Oh);
    // 7) out GEMM (single-pass bf16, BK=32 double-buffered) -> f32 out
    gemm_out<<<dim3(M2c / 128, Cc / 64), 256, 0, stream>>>(Oh, WoT, out);
}

// Round 19
// 151.725 us; speedup vs baseline: 1.2095x; 1.0412x over previous
//
#include <hip/hip_runtime.h>
#include <math.h>

typedef unsigned short u16;
typedef unsigned int   u32;
typedef __attribute__((ext_vector_type(8)))  __bf16 bf16x8;
typedef __attribute__((ext_vector_type(16))) float  f32x16;

constexpr int Bc  = 4;
constexpr int Nc  = 2304;
constexpr int KSc = 8;
constexpr int Cc  = 512;
constexpr int Hc  = 8;
constexpr int Dc  = 64;
constexpr int NTc = Nc + KSc;          // 2312
constexpr int M1c = Bc * NTc;          // 9248
constexpr int N1c = 3 * Cc;            // 1536
constexpr int M2c = Bc * Nc;           // 9216
constexpr int QT128 = Nc / 128;        // 18 query tiles of 128
constexpr int KT64  = NTc / 64;        // 36 full tiles (+8 tail)
constexpr int NSPL  = 3;               // split-K factor
constexpr float LOG2E = 1.4426950408889634f;

__device__ __forceinline__ u32 f2bf1(float f) {
    u32 u = __float_as_uint(f);
    return (u + 0x7fffu + ((u >> 16) & 1u)) >> 16;   // RNE bf16
}
__device__ __forceinline__ u32 pk2(float lo, float hi) {
    u32 ul = __float_as_uint(lo);
    u32 uh = __float_as_uint(hi);
    ul = (ul + 0x7fffu + ((ul >> 16) & 1u)) >> 16;
    uh = (uh + 0x7fffu + ((uh >> 16) & 1u)) & 0xffff0000u;
    return ul | uh;
}
__device__ __forceinline__ float bf2f(u16 x) {
    return __uint_as_float(((u32)x) << 16);
}
__device__ __forceinline__ u32 pkb(float lo, float hi) {
    union { u32 u; __bf16 h[2]; } t;
    t.h[0] = (__bf16)lo; t.h[1] = (__bf16)hi;
    return t.u;
}
// async global->LDS, 16B per lane; LDS dest = wave base + lane*16 (linear)
__device__ __forceinline__ void gll16(const u16* g, char* l) {
    __builtin_amdgcn_global_load_lds(
        (const __attribute__((address_space(1))) unsigned int*)g,
        (__attribute__((address_space(3))) unsigned int*)l, 16, 0, 0);
}

#define MFMA32(A, B, C) __builtin_amdgcn_mfma_f32_32x32x16_bf16(A, B, C, 0, 0, 0)

union U4 { u32 u[4]; bf16x8 f; };

// ---------------------------------------------------------------------------
// concat(X,S) -> bf16 A [M1][512]
// ---------------------------------------------------------------------------
__global__ __launch_bounds__(256)
void cvt_concat(const float* __restrict__ X, const float* __restrict__ S,
                u16* __restrict__ A)
{
    const int id  = blockIdx.x * 256 + threadIdx.x;
    const int row = id >> 6;
    const int ch  = (id & 63) * 8;
    const int b = row / NTc, t = row - b * NTc;
    const float* src = (t < Nc) ? X + ((size_t)(b * Nc + t)) * Cc + ch
                                : S + ((size_t)(b * KSc + (t - Nc))) * Cc + ch;
    const float4 v0 = ((const float4*)src)[0];
    const float4 v1 = ((const float4*)src)[1];
    u32 w[4];
    w[0] = pk2(v0.x, v0.y); w[1] = pk2(v0.z, v0.w);
    w[2] = pk2(v1.x, v1.y); w[3] = pk2(v1.z, v1.w);
    *(uint4*)(A + (size_t)row * Cc + ch) = *(const uint4*)w;
}

// ---------------------------------------------------------------------------
// Transpose-cast weights: W [512][Nn] f32 -> WT [Nn][512] bf16
// ---------------------------------------------------------------------------
__global__ __launch_bounds__(256)
void cvt_w(const float* __restrict__ W, int Nn, u16* __restrict__ WT)
{
    __shared__ float Ws[64][68];
    const int n0 = blockIdx.x * 64, k0 = blockIdx.y * 64;
#pragma unroll
    for (int i = 0; i < 4; ++i) {
        const int c = i * 256 + threadIdx.x;
        const int kr = c >> 4, nc = (c & 15) * 4;
        const float4 v = *(const float4*)(W + (size_t)(k0 + kr) * Nn + n0 + nc);
        Ws[kr][nc] = v.x; Ws[kr][nc+1] = v.y; Ws[kr][nc+2] = v.z; Ws[kr][nc+3] = v.w;
    }
    __syncthreads();
#pragma unroll
    for (int i = 0; i < 2; ++i) {
        const int c = i * 256 + threadIdx.x;
        const int n = c >> 3, kc = (c & 7) * 8;
        u32 wh[4];
#pragma unroll
        for (int j = 0; j < 4; ++j)
            wh[j] = pk2(Ws[kc + 2*j][n], Ws[kc + 2*j + 1][n]);
        *(uint4*)(WT + (size_t)(n0 + n) * Cc + k0 + kc) = *(const uint4*)wh;
    }
}

// ---------------------------------------------------------------------------
// QKV GEMM, bf16 MFMA, global_load_lds double-buffered staging.
// Fused q/k L2-norm epilogue. V is written DIRECTLY TRANSPOSED into
// (B,H,D,Nt): acc fragment rows r=4g..4g+3 map to consecutive t, so each
// group is one aligned 8-byte store (values identical to the old path).
// ---------------------------------------------------------------------------
__global__ __launch_bounds__(256)
void gemm_qkv(const u16* __restrict__ A, const u16* __restrict__ Bw,
              const float* __restrict__ temp,
              u16* __restrict__ Qb, u16* __restrict__ Kb, u16* __restrict__ Vt)
{
    __shared__ __align__(16) u16 lds[2 * 2 * 8192];   // [buf][A/B] 16 KB each
    char* L = (char*)lds;

    const int tid = threadIdx.x;
    const int wid = tid >> 6, lane = tid & 63, hi = lane >> 5, ln = lane & 31;
    const int wm = wid >> 1, wn = wid & 1;
    const int m0 = blockIdx.x * 128, n0 = blockIdx.y * 128;

    const int sr = tid >> 3;
    const int sc = tid & 7;

    f32x16 acc[2][2];
#pragma unroll
    for (int i = 0; i < 2; ++i)
#pragma unroll
        for (int j = 0; j < 2; ++j)
#pragma unroll
            for (int r = 0; r < 16; ++r) acc[i][j][r] = 0.f;

#define QKV_STAGE(BUF, K0)                                                     \
    do {                                                                       \
        char* dA = L + (BUF) * 32768;                                          \
        char* dB = dA + 16384;                                                 \
        _Pragma("unroll")                                                      \
        for (int i_ = 0; i_ < 4; ++i_) {                                       \
            const int row_ = i_ * 32 + sr;                                     \
            const int gc_  = (sc ^ (row_ & 7)) * 8;                            \
            int mg_ = m0 + row_; if (mg_ > M1c - 1) mg_ = M1c - 1;             \
            gll16(A  + (size_t)mg_ * Cc + (K0) + gc_,                          \
                  dA + i_ * 4096 + tid * 16);                                  \
            gll16(Bw + (size_t)(n0 + row_) * Cc + (K0) + gc_,                  \
                  dB + i_ * 4096 + tid * 16);                                  \
        }                                                                      \
    } while (0)

    QKV_STAGE(0, 0);
    __syncthreads();

    for (int k0 = 0; k0 < Cc; k0 += 64) {
        const int cur = (k0 >> 6) & 1;
        if (k0 + 64 < Cc) QKV_STAGE(cur ^ 1, k0 + 64);
        const char* ldsA = L + cur * 32768;
        const char* ldsB = ldsA + 16384;
#pragma unroll
        for (int ks = 0; ks < 4; ++ks) {
            bf16x8 af[2], bfr[2];
#pragma unroll
            for (int f = 0; f < 2; ++f) {
                const int mr = wm * 64 + f * 32 + ln;
                af[f]  = *(const bf16x8*)(ldsA + mr * 128 + (((ks * 2 + hi) ^ (mr & 7)) << 4));
                const int nr = wn * 64 + f * 32 + ln;
                bfr[f] = *(const bf16x8*)(ldsB + nr * 128 + (((ks * 2 + hi) ^ (nr & 7)) << 4));
            }
#pragma unroll
            for (int fm = 0; fm < 2; ++fm)
#pragma unroll
                for (int fn = 0; fn < 2; ++fn)
                    acc[fm][fn] = MFMA32(af[fm], bfr[fn], acc[fm][fn]);
        }
        __syncthreads();
    }
#undef QKV_STAGE

    const int which = n0 >> 9;
    const int hh = ((n0 + wn * 64) >> 6) & 7;

    if (which < 2) {
        const float tsc = (which == 0) ? temp[hh] : 1.0f;
#pragma unroll
        for (int fm = 0; fm < 2; ++fm)
#pragma unroll
            for (int r = 0; r < 16; ++r) {
                float ss = fmaf(acc[fm][0][r], acc[fm][0][r],
                                acc[fm][1][r] * acc[fm][1][r]);
                ss += __shfl_xor(ss, 1);
                ss += __shfl_xor(ss, 2);
                ss += __shfl_xor(ss, 4);
                ss += __shfl_xor(ss, 8);
                ss += __shfl_xor(ss, 16);
                const float scl = tsc / fmaxf(sqrtf(ss), 1e-12f);
                acc[fm][0][r] *= scl;
                acc[fm][1][r] *= scl;
            }

#pragma unroll
        for (int fm = 0; fm < 2; ++fm)
#pragma unroll
            for (int fn = 0; fn < 2; ++fn) {
                const int ng = n0 + wn * 64 + fn * 32 + ln;
                const int h = (ng >> 6) & 7, d = ng & 63;
                u16* base = (which == 0) ? Qb : Kb;
#pragma unroll
                for (int r = 0; r < 16; ++r) {
                    const int mg = m0 + wm * 64 + fm * 32 + (r & 3) + 8 * (r >> 2) + 4 * hi;
                    if (mg < M1c) {
                        const int b = mg / NTc, t = mg - b * NTc;
                        base[((size_t)((b * Hc + h) * NTc + t)) * Dc + d] = (u16)f2bf1(acc[fm][fn][r]);
                    }
                }
            }
    } else {
        // V: write transposed (B,H,D,Nt); r=4g+j -> t consecutive, 8B stores
#pragma unroll
        for (int fm = 0; fm < 2; ++fm)
#pragma unroll
            for (int fn = 0; fn < 2; ++fn) {
                const int ng = n0 + wn * 64 + fn * 32 + ln;
                const int h = (ng >> 6) & 7, d = ng & 63;
#pragma unroll
                for (int g = 0; g < 4; ++g) {
                    const int mg = m0 + wm * 64 + fm * 32 + 8 * g + 4 * hi;
                    if (mg < M1c) {   // group of 4 never straddles (M1c%4==0, NTc%4==0)
                        const int b = mg / NTc, t = mg - b * NTc;
                        uint2 v;
                        v.x = f2bf1(acc[fm][fn][4*g])     | (f2bf1(acc[fm][fn][4*g+1]) << 16);
                        v.y = f2bf1(acc[fm][fn][4*g+2])   | (f2bf1(acc[fm][fn][4*g+3]) << 16);
                        *(uint2*)(Vt + ((size_t)((b * Hc + h) * Dc + d)) * NTc + t) = v;
                    }
                }
            }
    }
}

// ---------------------------------------------------------------------------
// Out GEMM, single-pass bf16, BK=32 double-buffered global_load_lds staging.
// ---------------------------------------------------------------------------
__global__ __launch_bounds__(256)
void gemm_out(const u16* __restrict__ Ahg, const u16* __restrict__ Bhg,
              float* __restrict__ Out)
{
    __shared__ __align__(16) u16 lds[2 * 6144];       // 2 x 12 KB
    char* L = (char*)lds;

    const int tid = threadIdx.x;
    const int wid = tid >> 6, lane = tid & 63, hi = lane >> 5, ln = lane & 31;
    const int wm = wid >> 1, wn = wid & 1;
    const int m0 = blockIdx.x * 128, n0 = blockIdx.y * 64;
    const int sr2 = tid >> 2;
    const int sc2 = tid & 3;

    f32x16 acc[2];
#pragma unroll
    for (int i = 0; i < 2; ++i)
#pragma unroll
        for (int r = 0; r < 16; ++r) acc[i][r] = 0.f;

#define OUT_STAGE(BUF, K0)                                                     \
    do {                                                                       \
        char* bb = L + (BUF) * 12288;                                          \
        _Pragma("unroll")                                                      \
        for (int i_ = 0; i_ < 2; ++i_) {                                       \
            const int row_ = i_ * 64 + sr2;                                    \
            const int gc_  = (sc2 ^ (row_ & 3)) * 8;                           \
            const size_t go_ = (size_t)(m0 + row_) * Cc + (K0) + gc_;          \
            gll16(Ahg + go_, bb + i_ * 4096 + tid * 16);                       \
        }                                                                      \
        {                                                                      \
            const int gc_  = (sc2 ^ (sr2 & 3)) * 8;                            \
            const size_t go_ = (size_t)(n0 + sr2) * Cc + (K0) + gc_;           \
            gll16(Bhg + go_, bb + 8192 + tid * 16);                            \
        }                                                                      \
    } while (0)

    OUT_STAGE(0, 0);
    __syncthreads();

    for (int k0 = 0; k0 < Cc; k0 += 32) {
        const int cur = (k0 >> 5) & 1;
        if (k0 + 32 < Cc) OUT_STAGE(cur ^ 1, k0 + 32);
        const char* bb = L + cur * 12288;
        const char* pAh = bb;
        const char* pBh = bb + 8192;
#pragma unroll
        for (int ks = 0; ks < 2; ++ks) {
            bf16x8 afh[2], bfh;
#pragma unroll
            for (int f = 0; f < 2; ++f) {
                const int mr = wm * 64 + f * 32 + ln;
                const int moff = mr * 64 + (((ks * 2 + hi) ^ (mr & 3)) << 4);
                afh[f] = *(const bf16x8*)(pAh + moff);
            }
            {
                const int nr = wn * 32 + ln;
                const int noff = nr * 64 + (((ks * 2 + hi) ^ (nr & 3)) << 4);
                bfh = *(const bf16x8*)(pBh + noff);
            }
#pragma unroll
            for (int fm = 0; fm < 2; ++fm)
                acc[fm] = MFMA32(afh[fm], bfh, acc[fm]);
        }
        __syncthreads();
    }
#undef OUT_STAGE

#pragma unroll
    for (int fm = 0; fm < 2; ++fm) {
        const int ng = n0 + wn * 32 + ln;
#pragma unroll
        for (int r = 0; r < 16; ++r) {
            const int mg = m0 + wm * 64 + fm * 32 + (r & 3) + 8 * (r >> 2) + 4 * hi;
            Out[(size_t)mg * Cc + ng] = acc[fm][r];
        }
    }
}

// ---------------------------------------------------------------------------
// MFMA flash attention, split-K x3, 4 waves x 32 queries (128 q/block).
// FROZEN round-12 register structure + XCD-aware block swizzle (T1).
// ---------------------------------------------------------------------------
__global__ __launch_bounds__(256)
void attn_mfma(const u16* __restrict__ Qbf, const u16* __restrict__ Kbf,
               const u16* __restrict__ Vtg, const float* __restrict__ temp,
               float* __restrict__ Op, float* __restrict__ Rs)
{
    __shared__ __align__(16) u16 ldsKV[2][2][4096];   // [buf][K/V] 8 KB each
    char* L = (char*)ldsKV;

    const int tid  = threadIdx.x;
    const int wid  = tid >> 6;
    const int lane = tid & 63;
    const int hi   = lane >> 5;
    const int ln   = lane & 31;
    // XCD-aware bijective swizzle (nwg = 1728 = 8*216, exact)
    const int blk  = (blockIdx.x & 7) * (Bc * Hc * QT128 * NSPL / 8)
                   + (blockIdx.x >> 3);
    const int sp   = blk % NSPL;               // key-range split 0..2
    const int qb   = blk / NSPL;
    const int bh   = qb / QT128;
    const int qt   = qb - bh * QT128;
    const int b    = bh >> 3, h = bh & 7;
    const int qbase = qt * 128 + wid * 32;
    const float mlc = fabsf(temp[h]) * LOG2E;
    const int ktb = (sp == 0) ? 0 : (sp == 1 ? 13 : 26);
    const int kte = (sp == 0) ? 13 : (sp == 1 ? 26 : (KT64 + 1));

    const u16* Qrow = Qbf + ((size_t)bh * NTc + qbase + ln) * Dc;
    bf16x8 qf[4];
#pragma unroll
    for (int ks = 0; ks < 4; ++ks)
        qf[ks] = *(const bf16x8*)(Qrow + ks * 16 + hi * 8);

    U4 ones;
    ones.u[0] = ones.u[1] = ones.u[2] = ones.u[3] = 0x3F803F80u;  // bf16 1.0 x8

    f32x16 o0, o1, rsacc;
#pragma unroll
    for (int r = 0; r < 16; ++r) { o0[r] = 0.f; o1[r] = 0.f; rsacc[r] = 0.f; }

    const u16* Kbh = Kbf + (size_t)bh * NTc * Dc;
    const u16* Vbh = Vtg + (size_t)bh * Dc * NTc;

    const int sc  = tid & 7;
    const int sr0 = tid >> 3;

#define ATTN_STAGE(BUF, KB)                                                    \
    do {                                                                       \
        char* Kd = L + (BUF) * 16384;                                          \
        char* Vd = Kd + 8192;                                                  \
        _Pragma("unroll")                                                      \
        for (int half_ = 0; half_ < 2; ++half_) {                              \
            const int r_ = sr0 + half_ * 32;                                   \
            const int gc_ = (sc ^ (r_ & 7)) * 8;                               \
            int rK = (KB) + r_;   if (rK > NTc - 1) rK = NTc - 1;              \
            int cV = (KB) + gc_;  if (cV > NTc - 8) cV = NTc - 8;              \
            gll16(Kbh + (size_t)rK * Dc + gc_, Kd + half_ * 4096 + tid * 16);  \
            gll16(Vbh + (size_t)r_ * NTc + cV, Vd + half_ * 4096 + tid * 16);  \
        }                                                                      \
    } while (0)

    ATTN_STAGE(0, ktb * 64);
    __syncthreads();

    for (int kt = ktb; kt < kte; ++kt) {
        const int  cur  = (kt - ktb) & 1;      // relative parity: any ktb
        const bool tail = (kt == KT64);
        if (kt + 1 < kte) ATTN_STAGE(cur ^ 1, (kt + 1) * 64);
        const char* Kc = L + cur * 16384;
        const char* Vc = Kc + 8192;

        const int nsub = tail ? 1 : 2;
        for (int kt2 = 0; kt2 < nsub; ++kt2) {
            f32x16 s;
#pragma unroll
            for (int r = 0; r < 16; ++r) s[r] = 0.f;
            const int krow = kt2 * 32 + ln;
            const char* kbc = Kc + (krow << 7);
            const int   ksz = (krow & 7) << 4;
            __builtin_amdgcn_s_setprio(1);
#pragma unroll
            for (int ks = 0; ks < 4; ++ks) {
                const bf16x8 kf = *(const bf16x8*)(kbc + (((ks << 5) + (hi << 4)) ^ ksz));
                s = MFMA32(kf, qf[ks], s);
            }
            __builtin_amdgcn_s_setprio(0);

            float p[16];
#pragma unroll
            for (int r = 0; r < 16; ++r)
                p[r] = __builtin_amdgcn_exp2f(fmaf(s[r], LOG2E, -mlc));
            if (tail) {
#pragma unroll
                for (int r = 4; r < 16; ++r) p[r] = 0.f;   // keys >= 8 invalid
            }

            u32 a0 = pkb(p[0],  p[1]),  a1 = pkb(p[2],  p[3]);
            u32 b0 = pkb(p[4],  p[5]),  b1 = pkb(p[6],  p[7]);
            u32 c0 = pkb(p[8],  p[9]),  c1 = pkb(p[10], p[11]);
            u32 d0 = pkb(p[12], p[13]), d1 = pkb(p[14], p[15]);
            asm("v_permlane32_swap_b32 %0, %1" : "+v"(a0), "+v"(b0));
            asm("v_permlane32_swap_b32 %0, %1" : "+v"(a1), "+v"(b1));
            asm("v_permlane32_swap_b32 %0, %1" : "+v"(c0), "+v"(d0));
            asm("v_permlane32_swap_b32 %0, %1" : "+v"(c1), "+v"(d1));
            U4 f0, f1;
            f0.u[0] = a0; f0.u[1] = a1; f0.u[2] = b0; f0.u[3] = b1;
            f1.u[0] = c0; f1.u[1] = c1; f1.u[2] = d0; f1.u[3] = d1;

            const char* v0c = Vc + (ln << 7);
            const char* v1c = Vc + ((32 + ln) << 7);
            const int   vsz0 = (ln & 7) << 4;
            const int   cof0 = ((kt2 << 6) + (hi << 4)) ^ vsz0;
            const int   cof1 = ((kt2 << 6) + 32 + (hi << 4)) ^ vsz0;
            __builtin_amdgcn_s_setprio(1);
            rsacc = MFMA32(ones.f, f0.f, rsacc);
            o0 = MFMA32(*(const bf16x8*)(v0c + cof0), f0.f, o0);
            o1 = MFMA32(*(const bf16x8*)(v1c + cof0), f0.f, o1);
            if (!tail) {
                rsacc = MFMA32(ones.f, f1.f, rsacc);
                o0 = MFMA32(*(const bf16x8*)(v0c + cof1), f1.f, o0);
                o1 = MFMA32(*(const bf16x8*)(v1c + cof1), f1.f, o1);
            }
            __builtin_amdgcn_s_setprio(0);
        }
        __syncthreads();
    }
#undef ATTN_STAGE

    if (hi == 0)
        Rs[((size_t)sp * 32 + bh) * Nc + qbase + ln] = rsacc[0];

    float* Po = Op + (size_t)sp * M2c * Cc
                   + ((size_t)b * Nc + qbase + ln) * Cc + h * Dc;
#pragma unroll
    for (int g = 0; g < 4; ++g) {
        *(float4*)(Po + 8 * g + 4 * hi) =
            make_float4(o0[4*g], o0[4*g+1], o0[4*g+2], o0[4*g+3]);
        *(float4*)(Po + 32 + 8 * g + 4 * hi) =
            make_float4(o1[4*g], o1[4*g+1], o1[4*g+2], o1[4*g+3]);
    }
}

// ---------------------------------------------------------------------------
// Merge split-K x3 partials: O = (Oa+Ob+Oc)/(rsa+rsb+rsc); bf16 (hi only).
// ---------------------------------------------------------------------------
__global__ __launch_bounds__(256)
void merge_o(const float* __restrict__ Op, const float* __restrict__ Rs,
             u16* __restrict__ Oh)
{
    const int id = blockIdx.x * 256 + threadIdx.x;    // 4 floats per thread
    const size_t base = (size_t)id * 4;
    const int row = id >> 7;
    const int c   = (int)(base & 511);
    const int b   = row / Nc, qi = row - b * Nc;
    const int bh  = b * Hc + (c >> 6);
    const float rs = Rs[(size_t)bh * Nc + qi]
                   + Rs[(size_t)(32 + bh) * Nc + qi]
                   + Rs[(size_t)(64 + bh) * Nc + qi];
    const float inv = 1.0f / rs;
    const float4 va = *(const float4*)(Op + base);
    const float4 vb = *(const float4*)(Op + (size_t)M2c * Cc + base);
    const float4 vc = *(const float4*)(Op + 2 * (size_t)M2c * Cc + base);
    uint2 hv;
    hv.x = pk2((va.x + vb.x + vc.x) * inv, (va.y + vb.y + vc.y) * inv);
    hv.y = pk2((va.z + vb.z + vc.z) * inv, (va.w + vb.w + vc.w) * inv);
    *(uint2*)(Oh + base) = hv;
}

// ---------------------------------------------------------------------------
extern "C" void kernel_launch(void* const* d_in, const int* in_sizes, int n_in,
                              void* d_out, int out_size, void* d_ws, size_t ws_size,
                              hipStream_t stream)
{
    const float* X    = (const float*)d_in[0];
    const float* S    = (const float*)d_in[1];
    const float* Wqkv = (const float*)d_in[2];
    const float* Wout = (const float*)d_in[3];
    const float* temp = (const float*)d_in[4];
    float* out = (float*)d_out;

    u16* ws16 = (u16*)d_ws;
    const size_t R  = (size_t)M1c * Cc;     // 4,734,976 u16
    const size_t RO = (size_t)M2c * Cc;     // 4,718,592

    // Op region: 3 x RO f32 = 6*RO u16, aliasing Abf and WqT (dead before
    // attn writes Op).
    float* Op  = (float*)ws16;
    u16*  Abf  = ws16;                      // [0, R)
    u16*  WqT  = ws16 + 2 * R;              // [2R, 2R+N1c*Cc)  << 6*RO
    u16*  WoT  = ws16 + 6 * RO;
    u16*  Qbf  = WoT + (size_t)Cc * Cc;
    u16*  Kbf  = Qbf + R;
    u16*  Vt   = Kbf + R;
    float* Rs  = (float*)(Vt + R);          // NSPL*32*Nc floats
    u16*  Oh   = Qbf;                       // alias: Qbf dead after attn

    // 1) input concat + bf16 cast
    cvt_concat<<<M1c * (Cc / 8) / 256, 256, 0, stream>>>(X, S, Abf);
    // 2) weight transpose-casts
    cvt_w<<<dim3(N1c / 64, Cc / 64), 256, 0, stream>>>(Wqkv, N1c, WqT);
    cvt_w<<<dim3(Cc  / 64, Cc / 64), 256, 0, stream>>>(Wout, Cc,  WoT);
    // 3) QKV GEMM with fused q/k normalization; V written pre-transposed
    gemm_qkv<<<dim3((M1c + 127) / 128, N1c / 128), 256, 0, stream>>>(Abf, WqT, temp, Qbf, Kbf, Vt);
    // 4) attention split-K x3 (XCD-swizzled) -> partials
    attn_mfma<<<Bc * Hc * QT128 * NSPL, 256, 0, stream>>>(Qbf, Kbf, Vt, temp, Op, Rs);
    // 5) merge partials -> Oattn bf16 (aliases dead Qbf)
    merge_o<<<(int)(RO / 4 / 256), 256, 0, stream>>>(Op, Rs, Oh);
    // 6) out GEMM (single-pass bf16, BK=32 double-buffered) -> f32 out
    gemm_out<<<dim3(M2c / 128, Cc / 64), 256, 0, stream>>>(Oh, WoT, out);
}

// Round 20
// 147.959 us; speedup vs baseline: 1.2403x; 1.0255x over previous
//
#include <hip/hip_runtime.h>
#include <math.h>

typedef unsigned short u16;
typedef unsigned int   u32;
typedef __attribute__((ext_vector_type(8)))  __bf16 bf16x8;
typedef __attribute__((ext_vector_type(16))) float  f32x16;

constexpr int Bc  = 4;
constexpr int Nc  = 2304;
constexpr int KSc = 8;
constexpr int Cc  = 512;
constexpr int Hc  = 8;
constexpr int Dc  = 64;
constexpr int NTc = Nc + KSc;          // 2312
constexpr int M1c = Bc * NTc;          // 9248
constexpr int N1c = 3 * Cc;            // 1536
constexpr int M2c = Bc * Nc;           // 9216
constexpr int QT128 = Nc / 128;        // 18 query tiles of 128
constexpr int KT64  = NTc / 64;        // 36 full tiles (+8 tail)
constexpr int NSPL  = 3;               // split-K factor
constexpr float LOG2E = 1.4426950408889634f;

__device__ __forceinline__ u32 f2bf1(float f) {
    u32 u = __float_as_uint(f);
    return (u + 0x7fffu + ((u >> 16) & 1u)) >> 16;   // RNE bf16
}
__device__ __forceinline__ u32 pk2(float lo, float hi) {
    u32 ul = __float_as_uint(lo);
    u32 uh = __float_as_uint(hi);
    ul = (ul + 0x7fffu + ((ul >> 16) & 1u)) >> 16;
    uh = (uh + 0x7fffu + ((uh >> 16) & 1u)) & 0xffff0000u;
    return ul | uh;
}
__device__ __forceinline__ float bf2f(u16 x) {
    return __uint_as_float(((u32)x) << 16);
}
__device__ __forceinline__ u32 pkb(float lo, float hi) {
    union { u32 u; __bf16 h[2]; } t;
    t.h[0] = (__bf16)lo; t.h[1] = (__bf16)hi;
    return t.u;
}
// async global->LDS, 16B per lane; LDS dest = wave base + lane*16 (linear)
__device__ __forceinline__ void gll16(const u16* g, char* l) {
    __builtin_amdgcn_global_load_lds(
        (const __attribute__((address_space(1))) unsigned int*)g,
        (__attribute__((address_space(3))) unsigned int*)l, 16, 0, 0);
}

#define MFMA32(A, B, C) __builtin_amdgcn_mfma_f32_32x32x16_bf16(A, B, C, 0, 0, 0)

union U4 { u32 u[4]; bf16x8 f; };

// ---------------------------------------------------------------------------
// concat(X,S) -> bf16 A [M1][512]
// ---------------------------------------------------------------------------
__global__ __launch_bounds__(256)
void cvt_concat(const float* __restrict__ X, const float* __restrict__ S,
                u16* __restrict__ A)
{
    const int id  = blockIdx.x * 256 + threadIdx.x;
    const int row = id >> 6;
    const int ch  = (id & 63) * 8;
    const int b = row / NTc, t = row - b * NTc;
    const float* src = (t < Nc) ? X + ((size_t)(b * Nc + t)) * Cc + ch
                                : S + ((size_t)(b * KSc + (t - Nc))) * Cc + ch;
    const float4 v0 = ((const float4*)src)[0];
    const float4 v1 = ((const float4*)src)[1];
    u32 w[4];
    w[0] = pk2(v0.x, v0.y); w[1] = pk2(v0.z, v0.w);
    w[2] = pk2(v1.x, v1.y); w[3] = pk2(v1.z, v1.w);
    *(uint4*)(A + (size_t)row * Cc + ch) = *(const uint4*)w;
}

// ---------------------------------------------------------------------------
// Transpose-cast BOTH weights in one launch:
//   blocks x < N1c/64 (=24): Wqkv [512][1536] -> WqT [1536][512]
//   blocks x >= 24 (8 more):  Wout [512][512]  -> WoT [512][512]
// ---------------------------------------------------------------------------
__global__ __launch_bounds__(256)
void cvt_w2(const float* __restrict__ Wqkv, const float* __restrict__ Wout,
            u16* __restrict__ WqT, u16* __restrict__ WoT)
{
    __shared__ float Ws[64][68];
    const bool second = (blockIdx.x >= N1c / 64);
    const float* W = second ? Wout : Wqkv;
    u16*        WT = second ? WoT  : WqT;
    const int   Nn = second ? Cc   : N1c;
    const int n0 = (second ? (blockIdx.x - N1c / 64) : blockIdx.x) * 64;
    const int k0 = blockIdx.y * 64;
#pragma unroll
    for (int i = 0; i < 4; ++i) {
        const int c = i * 256 + threadIdx.x;
        const int kr = c >> 4, nc = (c & 15) * 4;
        const float4 v = *(const float4*)(W + (size_t)(k0 + kr) * Nn + n0 + nc);
        Ws[kr][nc] = v.x; Ws[kr][nc+1] = v.y; Ws[kr][nc+2] = v.z; Ws[kr][nc+3] = v.w;
    }
    __syncthreads();
#pragma unroll
    for (int i = 0; i < 2; ++i) {
        const int c = i * 256 + threadIdx.x;
        const int n = c >> 3, kc = (c & 7) * 8;
        u32 wh[4];
#pragma unroll
        for (int j = 0; j < 4; ++j)
            wh[j] = pk2(Ws[kc + 2*j][n], Ws[kc + 2*j + 1][n]);
        *(uint4*)(WT + (size_t)(n0 + n) * Cc + k0 + kc) = *(const uint4*)wh;
    }
}

// ---------------------------------------------------------------------------
// QKV GEMM, bf16 MFMA, global_load_lds double-buffered staging.
// Fused q/k L2-norm epilogue; LOG2E folded into K's normalization (single
// f32->bf16 rounding, same lattice quality; attn then uses exp2 directly).
// V written directly transposed into (B,H,D,Nt).
// ---------------------------------------------------------------------------
__global__ __launch_bounds__(256)
void gemm_qkv(const u16* __restrict__ A, const u16* __restrict__ Bw,
              const float* __restrict__ temp,
              u16* __restrict__ Qb, u16* __restrict__ Kb, u16* __restrict__ Vt)
{
    __shared__ __align__(16) u16 lds[2 * 2 * 8192];   // [buf][A/B] 16 KB each
    char* L = (char*)lds;

    const int tid = threadIdx.x;
    const int wid = tid >> 6, lane = tid & 63, hi = lane >> 5, ln = lane & 31;
    const int wm = wid >> 1, wn = wid & 1;
    const int m0 = blockIdx.x * 128, n0 = blockIdx.y * 128;

    const int sr = tid >> 3;
    const int sc = tid & 7;

    f32x16 acc[2][2];
#pragma unroll
    for (int i = 0; i < 2; ++i)
#pragma unroll
        for (int j = 0; j < 2; ++j)
#pragma unroll
            for (int r = 0; r < 16; ++r) acc[i][j][r] = 0.f;

#define QKV_STAGE(BUF, K0)                                                     \
    do {                                                                       \
        char* dA = L + (BUF) * 32768;                                          \
        char* dB = dA + 16384;                                                 \
        _Pragma("unroll")                                                      \
        for (int i_ = 0; i_ < 4; ++i_) {                                       \
            const int row_ = i_ * 32 + sr;                                     \
            const int gc_  = (sc ^ (row_ & 7)) * 8;                            \
            int mg_ = m0 + row_; if (mg_ > M1c - 1) mg_ = M1c - 1;             \
            gll16(A  + (size_t)mg_ * Cc + (K0) + gc_,                          \
                  dA + i_ * 4096 + tid * 16);                                  \
            gll16(Bw + (size_t)(n0 + row_) * Cc + (K0) + gc_,                  \
                  dB + i_ * 4096 + tid * 16);                                  \
        }                                                                      \
    } while (0)

    QKV_STAGE(0, 0);
    __syncthreads();

    for (int k0 = 0; k0 < Cc; k0 += 64) {
        const int cur = (k0 >> 6) & 1;
        if (k0 + 64 < Cc) QKV_STAGE(cur ^ 1, k0 + 64);
        const char* ldsA = L + cur * 32768;
        const char* ldsB = ldsA + 16384;
#pragma unroll
        for (int ks = 0; ks < 4; ++ks) {
            bf16x8 af[2], bfr[2];
#pragma unroll
            for (int f = 0; f < 2; ++f) {
                const int mr = wm * 64 + f * 32 + ln;
                af[f]  = *(const bf16x8*)(ldsA + mr * 128 + (((ks * 2 + hi) ^ (mr & 7)) << 4));
                const int nr = wn * 64 + f * 32 + ln;
                bfr[f] = *(const bf16x8*)(ldsB + nr * 128 + (((ks * 2 + hi) ^ (nr & 7)) << 4));
            }
#pragma unroll
            for (int fm = 0; fm < 2; ++fm)
#pragma unroll
                for (int fn = 0; fn < 2; ++fn)
                    acc[fm][fn] = MFMA32(af[fm], bfr[fn], acc[fm][fn]);
        }
        __syncthreads();
    }
#undef QKV_STAGE

    const int which = n0 >> 9;
    const int hh = ((n0 + wn * 64) >> 6) & 7;

    if (which < 2) {
        // q: scale by temp/||q||; k: scale by log2e/||k|| (attn uses exp2)
        const float tsc = (which == 0) ? temp[hh] : LOG2E;
#pragma unroll
        for (int fm = 0; fm < 2; ++fm)
#pragma unroll
            for (int r = 0; r < 16; ++r) {
                float ss = fmaf(acc[fm][0][r], acc[fm][0][r],
                                acc[fm][1][r] * acc[fm][1][r]);
                ss += __shfl_xor(ss, 1);
                ss += __shfl_xor(ss, 2);
                ss += __shfl_xor(ss, 4);
                ss += __shfl_xor(ss, 8);
                ss += __shfl_xor(ss, 16);
                const float scl = tsc / fmaxf(sqrtf(ss), 1e-12f);
                acc[fm][0][r] *= scl;
                acc[fm][1][r] *= scl;
            }

#pragma unroll
        for (int fm = 0; fm < 2; ++fm)
#pragma unroll
            for (int fn = 0; fn < 2; ++fn) {
                const int ng = n0 + wn * 64 + fn * 32 + ln;
                const int h = (ng >> 6) & 7, d = ng & 63;
                u16* base = (which == 0) ? Qb : Kb;
#pragma unroll
                for (int r = 0; r < 16; ++r) {
                    const int mg = m0 + wm * 64 + fm * 32 + (r & 3) + 8 * (r >> 2) + 4 * hi;
                    if (mg < M1c) {
                        const int b = mg / NTc, t = mg - b * NTc;
                        base[((size_t)((b * Hc + h) * NTc + t)) * Dc + d] = (u16)f2bf1(acc[fm][fn][r]);
                    }
                }
            }
    } else {
        // V: write transposed (B,H,D,Nt); r=4g+j -> t consecutive, 8B stores
#pragma unroll
        for (int fm = 0; fm < 2; ++fm)
#pragma unroll
            for (int fn = 0; fn < 2; ++fn) {
                const int ng = n0 + wn * 64 + fn * 32 + ln;
                const int h = (ng >> 6) & 7, d = ng & 63;
#pragma unroll
                for (int g = 0; g < 4; ++g) {
                    const int mg = m0 + wm * 64 + fm * 32 + 8 * g + 4 * hi;
                    if (mg < M1c) {
                        const int b = mg / NTc, t = mg - b * NTc;
                        uint2 v;
                        v.x = f2bf1(acc[fm][fn][4*g])   | (f2bf1(acc[fm][fn][4*g+1]) << 16);
                        v.y = f2bf1(acc[fm][fn][4*g+2]) | (f2bf1(acc[fm][fn][4*g+3]) << 16);
                        *(uint2*)(Vt + ((size_t)((b * Hc + h) * Dc + d)) * NTc + t) = v;
                    }
                }
            }
    }
}

// ---------------------------------------------------------------------------
// Out GEMM, single-pass bf16, BK=32 double-buffered global_load_lds staging.
// ---------------------------------------------------------------------------
__global__ __launch_bounds__(256)
void gemm_out(const u16* __restrict__ Ahg, const u16* __restrict__ Bhg,
              float* __restrict__ Out)
{
    __shared__ __align__(16) u16 lds[2 * 6144];       // 2 x 12 KB
    char* L = (char*)lds;

    const int tid = threadIdx.x;
    const int wid = tid >> 6, lane = tid & 63, hi = lane >> 5, ln = lane & 31;
    const int wm = wid >> 1, wn = wid & 1;
    const int m0 = blockIdx.x * 128, n0 = blockIdx.y * 64;
    const int sr2 = tid >> 2;
    const int sc2 = tid & 3;

    f32x16 acc[2];
#pragma unroll
    for (int i = 0; i < 2; ++i)
#pragma unroll
        for (int r = 0; r < 16; ++r) acc[i][r] = 0.f;

#define OUT_STAGE(BUF, K0)                                                     \
    do {                                                                       \
        char* bb = L + (BUF) * 12288;                                          \
        _Pragma("unroll")                                                      \
        for (int i_ = 0; i_ < 2; ++i_) {                                       \
            const int row_ = i_ * 64 + sr2;                                    \
            const int gc_  = (sc2 ^ (row_ & 3)) * 8;                           \
            const size_t go_ = (size_t)(m0 + row_) * Cc + (K0) + gc_;          \
            gll16(Ahg + go_, bb + i_ * 4096 + tid * 16);                       \
        }                                                                      \
        {                                                                      \
            const int gc_  = (sc2 ^ (sr2 & 3)) * 8;                            \
            const size_t go_ = (size_t)(n0 + sr2) * Cc + (K0) + gc_;           \
            gll16(Bhg + go_, bb + 8192 + tid * 16);                            \
        }                                                                      \
    } while (0)

    OUT_STAGE(0, 0);
    __syncthreads();

    for (int k0 = 0; k0 < Cc; k0 += 32) {
        const int cur = (k0 >> 5) & 1;
        if (k0 + 32 < Cc) OUT_STAGE(cur ^ 1, k0 + 32);
        const char* bb = L + cur * 12288;
        const char* pAh = bb;
        const char* pBh = bb + 8192;
#pragma unroll
        for (int ks = 0; ks < 2; ++ks) {
            bf16x8 afh[2], bfh;
#pragma unroll
            for (int f = 0; f < 2; ++f) {
                const int mr = wm * 64 + f * 32 + ln;
                const int moff = mr * 64 + (((ks * 2 + hi) ^ (mr & 3)) << 4);
                afh[f] = *(const bf16x8*)(pAh + moff);
            }
            {
                const int nr = wn * 32 + ln;
                const int noff = nr * 64 + (((ks * 2 + hi) ^ (nr & 3)) << 4);
                bfh = *(const bf16x8*)(pBh + noff);
            }
#pragma unroll
            for (int fm = 0; fm < 2; ++fm)
                acc[fm] = MFMA32(afh[fm], bfh, acc[fm]);
        }
        __syncthreads();
    }
#undef OUT_STAGE

#pragma unroll
    for (int fm = 0; fm < 2; ++fm) {
        const int ng = n0 + wn * 32 + ln;
#pragma unroll
        for (int r = 0; r < 16; ++r) {
            const int mg = m0 + wm * 64 + fm * 32 + (r & 3) + 8 * (r >> 2) + 4 * hi;
            Out[(size_t)mg * Cc + ng] = acc[fm][r];
        }
    }
}

// ---------------------------------------------------------------------------
// MFMA flash attention, split-K x3, 4 waves x 32 queries (128 q/block).
// FROZEN round-12 register structure + XCD swizzle. K is pre-scaled by
// log2e, so p = exp2(s - mlc) directly (no per-element fma).
// ---------------------------------------------------------------------------
__global__ __launch_bounds__(256)
void attn_mfma(const u16* __restrict__ Qbf, const u16* __restrict__ Kbf,
               const u16* __restrict__ Vtg, const float* __restrict__ temp,
               float* __restrict__ Op, float* __restrict__ Rs)
{
    __shared__ __align__(16) u16 ldsKV[2][2][4096];   // [buf][K/V] 8 KB each
    char* L = (char*)ldsKV;

    const int tid  = threadIdx.x;
    const int wid  = tid >> 6;
    const int lane = tid & 63;
    const int hi   = lane >> 5;
    const int ln   = lane & 31;
    // XCD-aware bijective swizzle (nwg = 1728 = 8*216, exact)
    const int blk  = (blockIdx.x & 7) * (Bc * Hc * QT128 * NSPL / 8)
                   + (blockIdx.x >> 3);
    const int sp   = blk % NSPL;               // key-range split 0..2
    const int qb   = blk / NSPL;
    const int bh   = qb / QT128;
    const int qt   = qb - bh * QT128;
    const int b    = bh >> 3, h = bh & 7;
    const int qbase = qt * 128 + wid * 32;
    const float mlc = fabsf(temp[h]) * LOG2E;  // shift in log2 domain
    const int ktb = (sp == 0) ? 0 : (sp == 1 ? 13 : 26);
    const int kte = (sp == 0) ? 13 : (sp == 1 ? 26 : (KT64 + 1));

    const u16* Qrow = Qbf + ((size_t)bh * NTc + qbase + ln) * Dc;
    bf16x8 qf[4];
#pragma unroll
    for (int ks = 0; ks < 4; ++ks)
        qf[ks] = *(const bf16x8*)(Qrow + ks * 16 + hi * 8);

    U4 ones;
    ones.u[0] = ones.u[1] = ones.u[2] = ones.u[3] = 0x3F803F80u;  // bf16 1.0 x8

    f32x16 o0, o1, rsacc;
#pragma unroll
    for (int r = 0; r < 16; ++r) { o0[r] = 0.f; o1[r] = 0.f; rsacc[r] = 0.f; }

    const u16* Kbh = Kbf + (size_t)bh * NTc * Dc;
    const u16* Vbh = Vtg + (size_t)bh * Dc * NTc;

    const int sc  = tid & 7;
    const int sr0 = tid >> 3;

#define ATTN_STAGE(BUF, KB)                                                    \
    do {                                                                       \
        char* Kd = L + (BUF) * 16384;                                          \
        char* Vd = Kd + 8192;                                                  \
        _Pragma("unroll")                                                      \
        for (int half_ = 0; half_ < 2; ++half_) {                              \
            const int r_ = sr0 + half_ * 32;                                   \
            const int gc_ = (sc ^ (r_ & 7)) * 8;                               \
            int rK = (KB) + r_;   if (rK > NTc - 1) rK = NTc - 1;              \
            int cV = (KB) + gc_;  if (cV > NTc - 8) cV = NTc - 8;              \
            gll16(Kbh + (size_t)rK * Dc + gc_, Kd + half_ * 4096 + tid * 16);  \
            gll16(Vbh + (size_t)r_ * NTc + cV, Vd + half_ * 4096 + tid * 16);  \
        }                                                                      \
    } while (0)

    ATTN_STAGE(0, ktb * 64);
    __syncthreads();

    for (int kt = ktb; kt < kte; ++kt) {
        const int  cur  = (kt - ktb) & 1;      // relative parity: any ktb
        const bool tail = (kt == KT64);
        if (kt + 1 < kte) ATTN_STAGE(cur ^ 1, (kt + 1) * 64);
        const char* Kc = L + cur * 16384;
        const char* Vc = Kc + 8192;

        const int nsub = tail ? 1 : 2;
        for (int kt2 = 0; kt2 < nsub; ++kt2) {
            f32x16 s;
#pragma unroll
            for (int r = 0; r < 16; ++r) s[r] = 0.f;
            const int krow = kt2 * 32 + ln;
            const char* kbc = Kc + (krow << 7);
            const int   ksz = (krow & 7) << 4;
            __builtin_amdgcn_s_setprio(1);
#pragma unroll
            for (int ks = 0; ks < 4; ++ks) {
                const bf16x8 kf = *(const bf16x8*)(kbc + (((ks << 5) + (hi << 4)) ^ ksz));
                s = MFMA32(kf, qf[ks], s);
            }
            __builtin_amdgcn_s_setprio(0);

            float p[16];
#pragma unroll
            for (int r = 0; r < 16; ++r)
                p[r] = __builtin_amdgcn_exp2f(s[r] - mlc);   // K pre-scaled by log2e
            if (tail) {
#pragma unroll
                for (int r = 4; r < 16; ++r) p[r] = 0.f;   // keys >= 8 invalid
            }

            u32 a0 = pkb(p[0],  p[1]),  a1 = pkb(p[2],  p[3]);
            u32 b0 = pkb(p[4],  p[5]),  b1 = pkb(p[6],  p[7]);
            u32 c0 = pkb(p[8],  p[9]),  c1 = pkb(p[10], p[11]);
            u32 d0 = pkb(p[12], p[13]), d1 = pkb(p[14], p[15]);
            asm("v_permlane32_swap_b32 %0, %1" : "+v"(a0), "+v"(b0));
            asm("v_permlane32_swap_b32 %0, %1" : "+v"(a1), "+v"(b1));
            asm("v_permlane32_swap_b32 %0, %1" : "+v"(c0), "+v"(d0));
            asm("v_permlane32_swap_b32 %0, %1" : "+v"(c1), "+v"(d1));
            U4 f0, f1;
            f0.u[0] = a0; f0.u[1] = a1; f0.u[2] = b0; f0.u[3] = b1;
            f1.u[0] = c0; f1.u[1] = c1; f1.u[2] = d0; f1.u[3] = d1;

            const char* v0c = Vc + (ln << 7);
            const char* v1c = Vc + ((32 + ln) << 7);
            const int   vsz0 = (ln & 7) << 4;
            const int   cof0 = ((kt2 << 6) + (hi << 4)) ^ vsz0;
            const int   cof1 = ((kt2 << 6) + 32 + (hi << 4)) ^ vsz0;
            __builtin_amdgcn_s_setprio(1);
            rsacc = MFMA32(ones.f, f0.f, rsacc);
            o0 = MFMA32(*(const bf16x8*)(v0c + cof0), f0.f, o0);
            o1 = MFMA32(*(const bf16x8*)(v1c + cof0), f0.f, o1);
            if (!tail) {
                rsacc = MFMA32(ones.f, f1.f, rsacc);
                o0 = MFMA32(*(const bf16x8*)(v0c + cof1), f1.f, o0);
                o1 = MFMA32(*(const bf16x8*)(v1c + cof1), f1.f, o1);
            }
            __builtin_amdgcn_s_setprio(0);
        }
        __syncthreads();
    }
#undef ATTN_STAGE

    if (hi == 0)
        Rs[((size_t)sp * 32 + bh) * Nc + qbase + ln] = rsacc[0];

    float* Po = Op + (size_t)sp * M2c * Cc
                   + ((size_t)b * Nc + qbase + ln) * Cc + h * Dc;
#pragma unroll
    for (int g = 0; g < 4; ++g) {
        *(float4*)(Po + 8 * g + 4 * hi) =
            make_float4(o0[4*g], o0[4*g+1], o0[4*g+2], o0[4*g+3]);
        *(float4*)(Po + 32 + 8 * g + 4 * hi) =
            make_float4(o1[4*g], o1[4*g+1], o1[4*g+2], o1[4*g+3]);
    }
}

// ---------------------------------------------------------------------------
// Merge split-K x3 partials: O = (Oa+Ob+Oc)/(rsa+rsb+rsc); bf16 (hi only).
// ---------------------------------------------------------------------------
__global__ __launch_bounds__(256)
void merge_o(const float* __restrict__ Op, const float* __restrict__ Rs,
             u16* __restrict__ Oh)
{
    const int id = blockIdx.x * 256 + threadIdx.x;    // 4 floats per thread
    const size_t base = (size_t)id * 4;
    const int row = id >> 7;
    const int c   = (int)(base & 511);
    const int b   = row / Nc, qi = row - b * Nc;
    const int bh  = b * Hc + (c >> 6);
    const float rs = Rs[(size_t)bh * Nc + qi]
                   + Rs[(size_t)(32 + bh) * Nc + qi]
                   + Rs[(size_t)(64 + bh) * Nc + qi];
    const float inv = 1.0f / rs;
    const float4 va = *(const float4*)(Op + base);
    const float4 vb = *(const float4*)(Op + (size_t)M2c * Cc + base);
    const float4 vc = *(const float4*)(Op + 2 * (size_t)M2c * Cc + base);
    uint2 hv;
    hv.x = pk2((va.x + vb.x + vc.x) * inv, (va.y + vb.y + vc.y) * inv);
    hv.y = pk2((va.z + vb.z + vc.z) * inv, (va.w + vb.w + vc.w) * inv);
    *(uint2*)(Oh + base) = hv;
}

// ---------------------------------------------------------------------------
extern "C" void kernel_launch(void* const* d_in, const int* in_sizes, int n_in,
                              void* d_out, int out_size, void* d_ws, size_t ws_size,
                              hipStream_t stream)
{
    const float* X    = (const float*)d_in[0];
    const float* S    = (const float*)d_in[1];
    const float* Wqkv = (const float*)d_in[2];
    const float* Wout = (const float*)d_in[3];
    const float* temp = (const float*)d_in[4];
    float* out = (float*)d_out;

    u16* ws16 = (u16*)d_ws;
    const size_t R  = (size_t)M1c * Cc;     // 4,734,976 u16
    const size_t RO = (size_t)M2c * Cc;     // 4,718,592

    // Op region: 3 x RO f32 = 6*RO u16, aliasing Abf and WqT (dead before
    // attn writes Op).
    float* Op  = (float*)ws16;
    u16*  Abf  = ws16;                      // [0, R)
    u16*  WqT  = ws16 + 2 * R;              // [2R, 2R+N1c*Cc)  << 6*RO
    u16*  WoT  = ws16 + 6 * RO;
    u16*  Qbf  = WoT + (size_t)Cc * Cc;
    u16*  Kbf  = Qbf + R;
    u16*  Vt   = Kbf + R;
    float* Rs  = (float*)(Vt + R);          // NSPL*32*Nc floats
    u16*  Oh   = Qbf;                       // alias: Qbf dead after attn

    // 1) input concat + bf16 cast
    cvt_concat<<<M1c * (Cc / 8) / 256, 256, 0, stream>>>(X, S, Abf);
    // 2) both weight transpose-casts in one launch
    cvt_w2<<<dim3(N1c / 64 + Cc / 64, Cc / 64), 256, 0, stream>>>(Wqkv, Wout, WqT, WoT);
    // 3) QKV GEMM with fused q/k normalization (k pre-scaled by log2e);
    //    V written pre-transposed
    gemm_qkv<<<dim3((M1c + 127) / 128, N1c / 128), 256, 0, stream>>>(Abf, WqT, temp, Qbf, Kbf, Vt);
    // 4) attention split-K x3 (XCD-swizzled, exp2 path) -> partials
    attn_mfma<<<Bc * Hc * QT128 * NSPL, 256, 0, stream>>>(Qbf, Kbf, Vt, temp, Op, Rs);
    // 5) merge partials -> Oattn bf16 (aliases dead Qbf)
    merge_o<<<(int)(RO / 4 / 256), 256, 0, stream>>>(Op, Rs, Oh);
    // 6) out GEMM (single-pass bf16, BK=32 double-buffered) -> f32 out
    gemm_out<<<dim3(M2c / 128, Cc / 64), 256, 0, stream>>>(Oh, WoT, out);
}